// Round 18
// baseline (1318.634 us; speedup 1.0000x reference)
//
#include <hip/hip_runtime.h>

#define NF 32
#define EPSF 1e-9f

// sort keyspace: [0,262144) morton3@64 ; [262144 + g*65536) pair g morton2@256
#define KSORT 458752
// coarse visit keyspace (visit lists only for coarse grids)
#define VO16 0
#define VO32 4096
#define VO64Q 36864
#define VO128Q 49152
#define KVIS2 98304
// grid layout (all 12 grids)
#define KO16 0
#define KO32 4096
#define KO64 36864
#define KO64Q 299008
#define KO128Q 311296
#define KO256Q 360448
#define KVIS 557056

__device__ __forceinline__ int cell_coord(float xv, int R, float& fr) {
  float x = xv * (float)(R - 1);
  int i0 = (int)floorf(x);
  i0 = min(max(i0, 0), R - 2);
  fr = x - (float)i0;
  return i0;
}
__device__ __forceinline__ float bf2f(unsigned short u) {
  return __uint_as_float((unsigned)u << 16);
}
__device__ __forceinline__ unsigned short f2bf(float x) {
  unsigned b = __float_as_uint(x);
  return (unsigned short)((b + 0x7FFF + ((b >> 16) & 1)) >> 16);
}
__device__ __forceinline__ unsigned p1b2(unsigned x) {
  x &= 0x3FF;
  x = (x | (x << 16)) & 0x030000FF;
  x = (x | (x << 8)) & 0x0300F00F;
  x = (x | (x << 4)) & 0x030C30C3;
  x = (x | (x << 2)) & 0x09249249;
  return x;
}
__device__ __forceinline__ unsigned p1b1(unsigned x) {
  x &= 0xFFFF;
  x = (x | (x << 8)) & 0x00FF00FF;
  x = (x | (x << 4)) & 0x0F0F0F0F;
  x = (x | (x << 2)) & 0x33333333;
  x = (x | (x << 1)) & 0x55555555;
  return x;
}
__device__ __forceinline__ unsigned c1b2(unsigned x) {
  x &= 0x09249249u;
  x = (x | (x >> 2)) & 0x030C30C3u;
  x = (x | (x >> 4)) & 0x0300F00Fu;
  x = (x | (x >> 8)) & 0x030000FFu;
  x = (x | (x >> 16)) & 0x3FFu;
  return x;
}
__device__ __forceinline__ unsigned c1b1(unsigned x) {
  x &= 0x55555555u;
  x = (x | (x >> 1)) & 0x33333333u;
  x = (x | (x >> 2)) & 0x0F0F0F0Fu;
  x = (x | (x >> 4)) & 0x00FF00FFu;
  x = (x | (x >> 8)) & 0xFFFFu;
  return x;
}

__device__ __forceinline__ int xcd_swz(int bid, int n) {
  return (bid & 7) * (n >> 3) + (bid >> 3);
}

// ---- wave-aggregated atomics over sorted-ish keys ----
__device__ __forceinline__ void agg_hist(int key, int* cnt) {
  int lane = threadIdx.x & 63;
  unsigned long long amask = __ballot(1);
  int nact = __popcll(amask);
  int prev = __shfl_up(key, 1);
  bool leader = (lane == 0) || (prev != key);
  unsigned long long lmask = __ballot(leader);
  if (leader) {
    unsigned long long above = (lane < 63) ? (lmask >> (lane + 1)) : 0ULL;
    int next = above ? (lane + 1 + (__ffsll((unsigned long long)above) - 1)) : nact;
    atomicAdd(&cnt[key], next - lane);
  }
}
template <int NC>
__device__ __forceinline__ void agg_place_batch(const int (&key)[NC], int* cur,
                                                int (&pos)[NC]) {
  int lane = threadIdx.x & 63;
  unsigned long long amask = __ballot(1);
  int nact = __popcll(amask);
  int ret[NC];
  int lp[NC];
#pragma unroll
  for (int c = 0; c < NC; ++c) {
    int prev = __shfl_up(key[c], 1);
    bool leader = (lane == 0) || (prev != key[c]);
    unsigned long long lmask = __ballot(leader);
    unsigned long long below = lmask & ((2ULL << lane) - 1ULL);
    lp[c] = 63 - __clzll((long long)below);
    ret[c] = 0;
    if (leader) {
      unsigned long long above = (lane < 63) ? (lmask >> (lane + 1)) : 0ULL;
      int next = above ? (lane + 1 + (__ffsll((unsigned long long)above) - 1)) : nact;
      ret[c] = atomicAdd(&cur[key[c]], next - lane);
    }
  }
#pragma unroll
  for (int c = 0; c < NC; ++c) pos[c] = __shfl(ret[c], lp[c]) + (lane - lp[c]);
}

// ---------------- fused sort keys: morton3@64 + 3 pair keys@256 ----------------
__global__ __launch_bounds__(256) void sort_hist_all(
    const float* __restrict__ xyz, int* __restrict__ cnt, int N) {
  int p = blockIdx.x * blockDim.x + threadIdx.x;
  if (p >= N) return;
  float fr;
  int c64[3], c256[3];
#pragma unroll
  for (int d = 0; d < 3; ++d) {
    c64[d] = cell_coord(xyz[p * 3 + d], 64, fr);
    c256[d] = cell_coord(xyz[p * 3 + d], 256, fr);
  }
  int k3 = (int)((p1b2((unsigned)c64[0]) << 2) | (p1b2((unsigned)c64[1]) << 1) |
                 p1b2((unsigned)c64[2]));
  atomicAdd(&cnt[k3], 1);
#pragma unroll
  for (int g = 0; g < 3; ++g) {
    int a = (g < 2) ? 0 : 1, b = (g == 0) ? 1 : 2;
    int key = 262144 + g * 65536 +
              (int)((p1b1((unsigned)c256[a]) << 1) | p1b1((unsigned)c256[b]));
    atomicAdd(&cnt[key], 1);
  }
}
__global__ __launch_bounds__(256) void sort_place_all(
    const float* __restrict__ xyz, int* __restrict__ cur, int* __restrict__ perm, int N) {
  int p = blockIdx.x * blockDim.x + threadIdx.x;
  if (p >= N) return;
  float fr;
  int c64[3], c256[3];
#pragma unroll
  for (int d = 0; d < 3; ++d) {
    c64[d] = cell_coord(xyz[p * 3 + d], 64, fr);
    c256[d] = cell_coord(xyz[p * 3 + d], 256, fr);
  }
  int k3 = (int)((p1b2((unsigned)c64[0]) << 2) | (p1b2((unsigned)c64[1]) << 1) |
                 p1b2((unsigned)c64[2]));
  perm[atomicAdd(&cur[k3], 1)] = p;
#pragma unroll
  for (int g = 0; g < 3; ++g) {
    int a = (g < 2) ? 0 : 1, b = (g == 0) ? 1 : 2;
    int key = 262144 + g * 65536 +
              (int)((p1b1((unsigned)c256[a]) << 1) | p1b1((unsigned)c256[b]));
    perm[atomicAdd(&cur[key], 1)] = p;
  }
}
__global__ __launch_bounds__(256) void permute_all(
    const float* __restrict__ xyz, const float* __restrict__ feat,
    const int* __restrict__ perm, float* __restrict__ xyz_s,
    unsigned short* __restrict__ feat_s, float* __restrict__ xy_g,
    unsigned short* __restrict__ feat_g, int N) {
  int t = blockIdx.x * blockDim.x + threadIdx.x;
  int s = t >> 5, f = t & 31;
  if (s >= 4 * N) return;
  int q = perm[s];
  float v = feat[(size_t)q * NF + f];
  if (s < N) {
    feat_s[(size_t)s * NF + f] = f2bf(v);
    if (f < 3) xyz_s[s * 3 + f] = xyz[q * 3 + f];
  } else {
    int sl = s - N;
    int g = sl / N;
    feat_g[(size_t)sl * NF + f] = f2bf(v);
    if (f < 2) {
      int a = (g < 2) ? 0 : 1, b = (g == 0) ? 1 : 2;
      xy_g[(size_t)sl * 2 + f] = xyz[q * 3 + (f == 0 ? a : b)];
    }
  }
}

// ---------------- scan (hierarchical, exclusive) ----------------
__global__ __launch_bounds__(256) void scan_blocksum(
    const int* __restrict__ cnt, int* __restrict__ bsum, int K) {
  __shared__ int red[256];
  int base = blockIdx.x * 2048 + threadIdx.x * 8;
  int s = 0;
#pragma unroll
  for (int j = 0; j < 8; ++j) {
    int k = base + j;
    if (k < K) s += cnt[k];
  }
  red[threadIdx.x] = s;
  __syncthreads();
  for (int off = 128; off > 0; off >>= 1) {
    if (threadIdx.x < off) red[threadIdx.x] += red[threadIdx.x + off];
    __syncthreads();
  }
  if (threadIdx.x == 0) bsum[blockIdx.x] = red[0];
}
__global__ __launch_bounds__(256) void scan_write(
    const int* __restrict__ cnt, const int* __restrict__ bsum,
    int* __restrict__ cur, int K) {
  __shared__ int lds[256];
  __shared__ int boff;
  int b = blockIdx.x, t = threadIdx.x;
  if (t == 0) {
    int s = 0;
    for (int j = 0; j < b; ++j) s += bsum[j];
    boff = s;
  }
  int base = b * 2048 + t * 8;
  int v[8];
  int s = 0;
#pragma unroll
  for (int j = 0; j < 8; ++j) {
    int k = base + j;
    v[j] = (k < K) ? cnt[k] : 0;
    s += v[j];
  }
  lds[t] = s;
  __syncthreads();
  for (int off = 1; off < 256; off <<= 1) {
    int add = (t >= off) ? lds[t - off] : 0;
    __syncthreads();
    lds[t] += add;
    __syncthreads();
  }
  int run = boff + lds[t] - s;
#pragma unroll
  for (int j = 0; j < 8; ++j) {
    int k = base + j;
    if (k < K) {
      cur[k] = run;
      run += v[j];
    }
  }
}

// ---------------- fused coarse hist: y=0..1 3D, y=2..7 2D(g,r) ----------------
__global__ __launch_bounds__(256) void hist_fused(
    const float* __restrict__ xyz_s, const float* __restrict__ xy_g,
    int* __restrict__ cnt, int N) {
  int y = blockIdx.y;
  int p = blockIdx.x * blockDim.x + threadIdx.x;
  if (p >= N) return;
  if (y < 2) {
    int R = 16 << y;
    int ko = (y == 0) ? VO16 : VO32;
    unsigned a0[3], a1[3];
    float fr[3];
#pragma unroll
    for (int d = 0; d < 3; ++d) {
      int i0 = cell_coord(xyz_s[p * 3 + d], R, fr[d]);
      a0[d] = p1b2((unsigned)i0);
      a1[d] = p1b2((unsigned)(i0 + 1));
    }
#pragma unroll
    for (int cb = 0; cb < 8; ++cb) {
      unsigned key = 0;
#pragma unroll
      for (int d = 0; d < 3; ++d) {
        int o = (cb >> d) & 1;
        key |= (o ? a1[d] : a0[d]) << (2 - d);
      }
      agg_hist(ko + (int)key, cnt);
    }
  } else {
    int idx = y - 2;
    int g = idx >> 1, r = idx & 1;
    int sl = g * N + p;
    int R = 64 << r;
    int kb = (r == 0) ? VO64Q : VO128Q;
    int base = kb + g * R * R;
    float frx, fry;
    int ix = cell_coord(xy_g[(size_t)sl * 2 + 0], R, frx);
    int iy = cell_coord(xy_g[(size_t)sl * 2 + 1], R, fry);
    unsigned ax0 = p1b1((unsigned)ix), ax1 = p1b1((unsigned)(ix + 1));
    unsigned ay0 = p1b1((unsigned)iy), ay1 = p1b1((unsigned)(iy + 1));
#pragma unroll
    for (int cb = 0; cb < 4; ++cb) {
      int o0 = (cb >> 1) & 1, o1 = cb & 1;
      agg_hist(base + (int)(((o0 ? ax1 : ax0) << 1) | (o1 ? ay1 : ay0)), cnt);
    }
  }
}

// ---------------- fused coarse placement (atomic): y=0..1 3D, y=2..7 2D ----------------
__global__ __launch_bounds__(256) void place_fused(
    const float* __restrict__ xyz_s, const float* __restrict__ xy_g,
    int* __restrict__ cur_v, int2* __restrict__ visits, int N) {
  int y = blockIdx.y;
  int p = blockIdx.x * blockDim.x + threadIdx.x;
  if (p >= N) return;
  if (y < 2) {
    int R = 16 << y;
    int ko = (y == 0) ? VO16 : VO32;
    unsigned a0[3], a1[3];
    float fr[3];
#pragma unroll
    for (int d = 0; d < 3; ++d) {
      int i0 = cell_coord(xyz_s[p * 3 + d], R, fr[d]);
      a0[d] = p1b2((unsigned)i0);
      a1[d] = p1b2((unsigned)(i0 + 1));
    }
    int keys[8];
    float ws[8];
#pragma unroll
    for (int cb = 0; cb < 8; ++cb) {
      float w = 1.f;
      unsigned key = 0;
#pragma unroll
      for (int d = 0; d < 3; ++d) {
        int o = (cb >> d) & 1;
        w *= o ? fr[d] : (1.f - fr[d]);
        key |= (o ? a1[d] : a0[d]) << (2 - d);
      }
      keys[cb] = ko + (int)key;
      ws[cb] = w;
    }
    int pos[8];
    agg_place_batch<8>(keys, cur_v, pos);
#pragma unroll
    for (int cb = 0; cb < 8; ++cb)
      visits[pos[cb]] = make_int2(p, __float_as_int(ws[cb]));
  } else {
    int idx = y - 2;
    int g = idx >> 1, r = idx & 1;
    int sl = g * N + p;
    int R = 64 << r;
    int kb = (r == 0) ? VO64Q : VO128Q;
    int base = kb + g * R * R;
    float frx, fry;
    int ix = cell_coord(xy_g[(size_t)sl * 2 + 0], R, frx);
    int iy = cell_coord(xy_g[(size_t)sl * 2 + 1], R, fry);
    unsigned ax0 = p1b1((unsigned)ix), ax1 = p1b1((unsigned)(ix + 1));
    unsigned ay0 = p1b1((unsigned)iy), ay1 = p1b1((unsigned)(iy + 1));
    int keys[4];
    float ws[4];
#pragma unroll
    for (int cb = 0; cb < 4; ++cb) {
      int o0 = (cb >> 1) & 1, o1 = cb & 1;
      ws[cb] = (o0 ? frx : 1.f - frx) * (o1 ? fry : 1.f - fry);
      keys[cb] = base + (int)(((o0 ? ax1 : ax0) << 1) | (o1 ? ay1 : ay0));
    }
    int pos[4];
    agg_place_batch<4>(keys, cur_v, pos);
#pragma unroll
    for (int cb = 0; cb < 4; ++cb)
      visits[pos[cb]] = make_int2(sl, __float_as_int(ws[cb]));
  }
}

// ---------------- fused create: block-per-cell over 4 coarse segments ----------------
__global__ __launch_bounds__(256) void create_block_fused(
    const unsigned short* __restrict__ feat_s, const unsigned short* __restrict__ feat_g,
    const int* __restrict__ cnt, const int* __restrict__ cur_end,
    const int2* __restrict__ visits, unsigned short* __restrict__ grid) {
  __shared__ int2 vlds[1024];
  __shared__ float2 lacc[256];
  __shared__ float lw[16];
  int bid = blockIdx.x;
  int vo, go, base, nseg;
  const unsigned short* feat;
  if (bid < 4096) {
    vo = VO16; go = KO16; base = 0; nseg = 4096; feat = feat_s;
  } else if (bid < 36864) {
    vo = VO32; go = KO32; base = 4096; nseg = 32768; feat = feat_s;
  } else if (bid < 49152) {
    vo = VO64Q; go = KO64Q; base = 36864; nseg = 12288; feat = feat_g;
  } else {
    vo = VO128Q; go = KO128Q; base = 49152; nseg = 49152; feat = feat_g;
  }
  int idx = xcd_swz(bid - base, nseg);
  int vcell = vo + idx;
  int e = cur_end[vcell];
  int n = cnt[vcell];
  int beg = e - n;
  for (int i = threadIdx.x; i < n && i < 1024; i += 256) vlds[i] = visits[beg + i];
  __syncthreads();
  bool inl = (n <= 1024);
  int slot = threadIdx.x >> 4;
  int fp = threadIdx.x & 15;
  float2 acc = {0.f, 0.f};
  float wsum = 0.f;
  int i = slot;
  for (; i + 16 < n; i += 32) {
    int2 v0 = inl ? vlds[i] : visits[beg + i];
    int2 v1 = inl ? vlds[i + 16] : visits[beg + i + 16];
    unsigned u0 = *(const unsigned*)(feat + (size_t)v0.x * NF + 2 * fp);
    unsigned u1 = *(const unsigned*)(feat + (size_t)v1.x * NF + 2 * fp);
    float w0 = __int_as_float(v0.y), w1 = __int_as_float(v1.y);
    acc.x = fmaf(w0, bf2f((unsigned short)u0), acc.x);
    acc.y = fmaf(w0, bf2f((unsigned short)(u0 >> 16)), acc.y);
    acc.x = fmaf(w1, bf2f((unsigned short)u1), acc.x);
    acc.y = fmaf(w1, bf2f((unsigned short)(u1 >> 16)), acc.y);
    wsum += w0 + w1;
  }
  if (i < n) {
    int2 v = inl ? vlds[i] : visits[beg + i];
    unsigned u = *(const unsigned*)(feat + (size_t)v.x * NF + 2 * fp);
    float w = __int_as_float(v.y);
    acc.x = fmaf(w, bf2f((unsigned short)u), acc.x);
    acc.y = fmaf(w, bf2f((unsigned short)(u >> 16)), acc.y);
    wsum += w;
  }
  lacc[threadIdx.x] = acc;
  if (fp == 0) lw[slot] = wsum;
  __syncthreads();
  if (threadIdx.x < 16) {
    float2 a = {0.f, 0.f};
    float w = 0.f;
#pragma unroll
    for (int s = 0; s < 16; ++s) {
      float2 t = lacc[s * 16 + threadIdx.x];
      a.x += t.x;
      a.y += t.y;
      w += lw[s];
    }
    float inv = 1.f / fmaxf(w, EPSF);
    unsigned short lo = f2bf(a.x * inv), hi = f2bf(a.y * inv);
    *(unsigned*)(grid + (size_t)(go + idx) * NF + 2 * threadIdx.x) =
        (unsigned)lo | ((unsigned)hi << 16);
  }
}

// ---------------- brick-LDS create for fine grids (64^3, 256^2) ----------------
// bid < 1024: 64^3 brick (4x8x8 cells); else 256^2 brick (16x16), 768 bricks.
__global__ __launch_bounds__(256) void create_brick_fused(
    const float* __restrict__ xyz_s, const unsigned short* __restrict__ feat_s,
    const float* __restrict__ xy_g, const unsigned short* __restrict__ feat_g,
    const int* __restrict__ cnt_all, const int* __restrict__ cur_all,
    unsigned short* __restrict__ grid, int N) {
  __shared__ float facc[8192];
  __shared__ float fw[256];
  __shared__ int2 blist[1024];
  __shared__ int bcount;
  int t = threadIdx.x;
  for (int i = t; i < 8192; i += 256) facc[i] = 0.f;
  fw[t] = 0.f;
  if (t == 0) bcount = 0;
  __syncthreads();
  int bid = blockIdx.x;
  int f = t & 31, pg = t >> 5;  // 8 point-groups of 32 feature lanes
  if (bid < 1024) {
    int b = xcd_swz(bid, 1024);
    int K = b << 8;
    int bx = (int)c1b2((unsigned)K >> 2), by = (int)c1b2((unsigned)K >> 1),
        bz = (int)c1b2((unsigned)K);
    // stage boundary homes (outside brick, -1 faces)
    if (t < 149) {
      int hx, hy, hz;
      if (t < 81) {
        hx = bx - 1; hy = by - 1 + t / 9; hz = bz - 1 + t % 9;
      } else if (t < 117) {
        int j = t - 81; hx = bx + j / 9; hy = by - 1; hz = bz - 1 + j % 9;
      } else {
        int j = t - 117; hx = bx + j / 8; hy = by + j % 8; hz = bz - 1;
      }
      if (hx >= 0 && hy >= 0 && hz >= 0 && hx < 64 && hy < 64 && hz < 64) {
        int hk = (int)((p1b2((unsigned)hx) << 2) | (p1b2((unsigned)hy) << 1) |
                       p1b2((unsigned)hz));
        int n = cnt_all[hk];
        if (n > 0) {
          int st = cur_all[hk] - n;
          int lb = atomicAdd(&bcount, n);
          int pk = (hx - bx + 1) | ((hy - by + 1) << 8) | ((hz - bz + 1) << 16);
          for (int i = 0; i < n; ++i)
            if (lb + i < 1024) blist[lb + i] = make_int2(st + i, pk);
        }
      }
    }
    int S = cur_all[K] - cnt_all[K];
    int E = cur_all[K + 255];
    __syncthreads();
    int nb = min(bcount, 1024);
    // phase A: brick's own points (contiguous)
    for (int i = S + pg; i < E; i += 8) {
      float x = xyz_s[i * 3 + 0] * 63.0f;
      float y = xyz_s[i * 3 + 1] * 63.0f;
      float z = xyz_s[i * 3 + 2] * 63.0f;
      int hx = min(max((int)floorf(x), 0), 62);
      int hy = min(max((int)floorf(y), 0), 62);
      int hz = min(max((int)floorf(z), 0), 62);
      float frx = x - (float)hx, fry = y - (float)hy, frz = z - (float)hz;
      float fv = bf2f(feat_s[(size_t)i * NF + f]);
      int lx0 = hx - bx, ly0 = hy - by, lz0 = hz - bz;
#pragma unroll
      for (int cb = 0; cb < 8; ++cb) {
        int lx = lx0 + (cb & 1), ly = ly0 + ((cb >> 1) & 1), lz = lz0 + ((cb >> 2) & 1);
        if ((unsigned)lx < 4u && (unsigned)ly < 8u && (unsigned)lz < 8u) {
          float w = ((cb & 1) ? frx : 1.f - frx) *
                    (((cb >> 1) & 1) ? fry : 1.f - fry) *
                    (((cb >> 2) & 1) ? frz : 1.f - frz);
          int lin = lx * 64 + ly * 8 + lz;
          atomicAdd(&facc[lin * 32 + f], w * fv);
          if (f == 0) atomicAdd(&fw[lin], w);
        }
      }
    }
    // phase B: boundary-home points
    for (int i = pg; i < nb; i += 8) {
      int2 e2 = blist[i];
      int q = e2.x;
      int dx = (e2.y & 255) - 1, dy = ((e2.y >> 8) & 255) - 1, dz = ((e2.y >> 16) & 255) - 1;
      float x = xyz_s[q * 3 + 0] * 63.0f;
      float y = xyz_s[q * 3 + 1] * 63.0f;
      float z = xyz_s[q * 3 + 2] * 63.0f;
      float frx = x - (float)(bx + dx), fry = y - (float)(by + dy),
            frz = z - (float)(bz + dz);
      float fv = bf2f(feat_s[(size_t)q * NF + f]);
#pragma unroll
      for (int cb = 0; cb < 8; ++cb) {
        int lx = dx + (cb & 1), ly = dy + ((cb >> 1) & 1), lz = dz + ((cb >> 2) & 1);
        if ((unsigned)lx < 4u && (unsigned)ly < 8u && (unsigned)lz < 8u) {
          float w = ((cb & 1) ? frx : 1.f - frx) *
                    (((cb >> 1) & 1) ? fry : 1.f - fry) *
                    (((cb >> 2) & 1) ? frz : 1.f - frz);
          int lin = lx * 64 + ly * 8 + lz;
          atomicAdd(&facc[lin * 32 + f], w * fv);
          if (f == 0) atomicAdd(&fw[lin], w);
        }
      }
    }
    __syncthreads();
    // writeback: contiguous keys [K, K+256)
    size_t gb = (size_t)(KO64 + K) * NF;
#pragma unroll
    for (int it = 0; it < 16; ++it) {
      int slot = it * 256 + t;
      int cm = slot >> 4, fp = slot & 15;
      int lz = (cm & 1) | ((cm >> 2) & 2) | ((cm >> 4) & 4);
      int ly = ((cm >> 1) & 1) | ((cm >> 3) & 2) | ((cm >> 5) & 4);
      int lx = ((cm >> 2) & 1) | ((cm >> 4) & 2);
      int lin = lx * 64 + ly * 8 + lz;
      float inv = 1.f / fmaxf(fw[lin], EPSF);
      unsigned short lo = f2bf(facc[lin * 32 + 2 * fp] * inv);
      unsigned short hi = f2bf(facc[lin * 32 + 2 * fp + 1] * inv);
      *(unsigned*)(grid + gb + (size_t)cm * NF + 2 * fp) =
          (unsigned)lo | ((unsigned)hi << 16);
    }
  } else {
    int b2 = xcd_swz(bid - 1024, 768);
    int g = b2 >> 8, mb = b2 & 255;
    int K0 = 262144 + g * 65536 + (mb << 8);
    int bx = (int)c1b1((unsigned)(mb << 8) >> 1), by = (int)c1b1((unsigned)(mb << 8));
    if (t < 33) {
      int hx, hy;
      if (t < 17) {
        hx = bx - 1; hy = by - 1 + t;
      } else {
        hx = bx + (t - 17); hy = by - 1;
      }
      if (hx >= 0 && hy >= 0 && hx < 256 && hy < 256) {
        int hk = 262144 + g * 65536 +
                 (int)((p1b1((unsigned)hx) << 1) | p1b1((unsigned)hy));
        int n = cnt_all[hk];
        if (n > 0) {
          int st = cur_all[hk] - n - N;
          int lb = atomicAdd(&bcount, n);
          int pk = (hx - bx + 1) | ((hy - by + 1) << 8);
          for (int i = 0; i < n; ++i)
            if (lb + i < 1024) blist[lb + i] = make_int2(st + i, pk);
        }
      }
    }
    int S = cur_all[K0] - cnt_all[K0] - N;
    int E = cur_all[K0 + 255] - N;
    __syncthreads();
    int nb = min(bcount, 1024);
    for (int i = S + pg; i < E; i += 8) {
      float x = xy_g[(size_t)i * 2 + 0] * 255.0f;
      float y = xy_g[(size_t)i * 2 + 1] * 255.0f;
      int hx = min(max((int)floorf(x), 0), 254);
      int hy = min(max((int)floorf(y), 0), 254);
      float frx = x - (float)hx, fry = y - (float)hy;
      float fv = bf2f(feat_g[(size_t)i * NF + f]);
      int lx0 = hx - bx, ly0 = hy - by;
#pragma unroll
      for (int cb = 0; cb < 4; ++cb) {
        int lx = lx0 + ((cb >> 1) & 1), ly = ly0 + (cb & 1);
        if ((unsigned)lx < 16u && (unsigned)ly < 16u) {
          float w = (((cb >> 1) & 1) ? frx : 1.f - frx) * ((cb & 1) ? fry : 1.f - fry);
          int lin = lx * 16 + ly;
          atomicAdd(&facc[lin * 32 + f], w * fv);
          if (f == 0) atomicAdd(&fw[lin], w);
        }
      }
    }
    for (int i = pg; i < nb; i += 8) {
      int2 e2 = blist[i];
      int q = e2.x;
      int dx = (e2.y & 255) - 1, dy = ((e2.y >> 8) & 255) - 1;
      float x = xy_g[(size_t)q * 2 + 0] * 255.0f;
      float y = xy_g[(size_t)q * 2 + 1] * 255.0f;
      float frx = x - (float)(bx + dx), fry = y - (float)(by + dy);
      float fv = bf2f(feat_g[(size_t)q * NF + f]);
#pragma unroll
      for (int cb = 0; cb < 4; ++cb) {
        int lx = dx + ((cb >> 1) & 1), ly = dy + (cb & 1);
        if ((unsigned)lx < 16u && (unsigned)ly < 16u) {
          float w = (((cb >> 1) & 1) ? frx : 1.f - frx) * ((cb & 1) ? fry : 1.f - fry);
          int lin = lx * 16 + ly;
          atomicAdd(&facc[lin * 32 + f], w * fv);
          if (f == 0) atomicAdd(&fw[lin], w);
        }
      }
    }
    __syncthreads();
    size_t gb = (size_t)(KO256Q + g * 65536 + (mb << 8)) * NF;
#pragma unroll
    for (int it = 0; it < 16; ++it) {
      int slot = it * 256 + t;
      int cm = slot >> 4, fp = slot & 15;
      int ly = (cm & 1) | ((cm >> 1) & 2) | ((cm >> 2) & 4) | ((cm >> 3) & 8);
      int lx = ((cm >> 1) & 1) | ((cm >> 2) & 2) | ((cm >> 3) & 4) | ((cm >> 4) & 8);
      int lin = lx * 16 + ly;
      float inv = 1.f / fmaxf(fw[lin], EPSF);
      unsigned short lo = f2bf(facc[lin * 32 + 2 * fp] * inv);
      unsigned short hi = f2bf(facc[lin * 32 + 2 * fp + 1] * inv);
      *(unsigned*)(grid + gb + (size_t)cm * NF + 2 * fp) =
          (unsigned)lo | ((unsigned)hi << 16);
    }
  }
}

// ---------------- fused encode: all 12 slots ----------------
__global__ __launch_bounds__(256) void encode_all(
    const float* __restrict__ xyz, const unsigned short* __restrict__ grid,
    float* __restrict__ out, int M) {
  int t = blockIdx.x * blockDim.x + threadIdx.x;
  int m = t >> 5, f = t & 31;
  if (m >= M) return;
  float X[3];
#pragma unroll
  for (int d = 0; d < 3; ++d) X[d] = xyz[m * 3 + d];
  {
    const int RS[3] = {16, 32, 64};
    const int KO[3] = {KO16, KO32, KO64};
#pragma unroll
    for (int r = 0; r < 3; ++r) {
      unsigned a0[3], a1[3];
      float fr[3];
#pragma unroll
      for (int d = 0; d < 3; ++d) {
        int i0 = cell_coord(X[d], RS[r], fr[d]);
        a0[d] = p1b2((unsigned)i0);
        a1[d] = p1b2((unsigned)(i0 + 1));
      }
      float acc = 0.f;
#pragma unroll
      for (int cb = 0; cb < 8; ++cb) {
        float w = 1.f;
        unsigned key = 0;
#pragma unroll
        for (int d = 0; d < 3; ++d) {
          int o = (cb >> d) & 1;
          w *= o ? fr[d] : (1.f - fr[d]);
          key |= (o ? a1[d] : a0[d]) << (2 - d);
        }
        acc = fmaf(w, bf2f(grid[(size_t)(KO[r] + (int)key) * NF + f]), acc);
      }
      out[(size_t)m * 384 + r * 32 + f] = acc;
    }
  }
  {
    const int RS[3] = {64, 128, 256};
    const int KB[3] = {KO64Q, KO128Q, KO256Q};
    const int RSQ[3] = {4096, 16384, 65536};
#pragma unroll
    for (int r = 0; r < 3; ++r) {
      unsigned b0[3], b1[3];
      float fr[3];
#pragma unroll
      for (int d = 0; d < 3; ++d) {
        int i0 = cell_coord(X[d], RS[r], fr[d]);
        b0[d] = p1b1((unsigned)i0);
        b1[d] = p1b1((unsigned)(i0 + 1));
      }
#pragma unroll
      for (int g = 0; g < 3; ++g) {
        int a = (g < 2) ? 0 : 1, b = (g == 0) ? 1 : 2;
        int base = KB[r] + g * RSQ[r];
        float acc = 0.f;
#pragma unroll
        for (int cb = 0; cb < 4; ++cb) {
          int o0 = (cb >> 1) & 1, o1 = cb & 1;
          float w = (o0 ? fr[a] : 1.f - fr[a]) * (o1 ? fr[b] : 1.f - fr[b]);
          int k = base + (int)(((o0 ? b1[a] : b0[a]) << 1) | (o1 ? b1[b] : b0[b]));
          acc = fmaf(w, bf2f(grid[(size_t)k * NF + f]), acc);
        }
        out[(size_t)m * 384 + (3 + g * 3 + r) * 32 + f] = acc;
      }
    }
  }
}

extern "C" void kernel_launch(void* const* d_in, const int* in_sizes, int n_in,
                              void* d_out, int out_size, void* d_ws, size_t ws_size,
                              hipStream_t stream) {
  const float* xyz_c = (const float*)d_in[0];
  const float* xyz_i = (const float*)d_in[1];
  const float* feat = (const float*)d_in[2];
  float* out = (float*)d_out;
  int N = in_sizes[0] / 3;
  int M = in_sizes[1] / 3;

  char* wsb = (char*)d_ws;
  size_t off = 0;
  auto al = [&](size_t bytes) {
    size_t o = off;
    off = (off + bytes + 255) & ~(size_t)255;
    return wsb + o;
  };
  const int KALL = KSORT + KVIS2;
  int* cnt_all = (int*)al((size_t)KALL * 4);
  int* cur_all = (int*)al((size_t)KALL * 4);
  int* bsum = (int*)al(4096);
  int* perm = (int*)al((size_t)4 * N * 4);
  float* xyz_s = (float*)al((size_t)N * 3 * 4);
  unsigned short* feat_s = (unsigned short*)al((size_t)N * NF * 2);
  float* xy_g = (float*)al((size_t)3 * N * 2 * 4);
  unsigned short* feat_g = (unsigned short*)al((size_t)3 * N * NF * 2);
  int2* visits = (int2*)al((size_t)40 * N * 8);
  unsigned short* grid = (unsigned short*)al((size_t)KVIS * NF * 2);

  int* cnt_v = cnt_all + KSORT;
  int* cur_v = cur_all + KSORT;

  int pb = (N + 255) / 256;
  int nbs = (KSORT + 2047) / 2048;
  int nbv = (KVIS2 + 2047) / 2048;

  hipMemsetAsync(cnt_all, 0, (size_t)KALL * 4, stream);

  // fused sort of all 4 point-orderings
  sort_hist_all<<<pb, 256, 0, stream>>>(xyz_c, cnt_all, N);
  scan_blocksum<<<nbs, 256, 0, stream>>>(cnt_all, bsum, KSORT);
  scan_write<<<nbs, 256, 0, stream>>>(cnt_all, bsum, cur_all, KSORT);
  sort_place_all<<<pb, 256, 0, stream>>>(xyz_c, cur_all, perm, N);
  permute_all<<<(4 * N * 32 + 255) / 256, 256, 0, stream>>>(xyz_c, feat, perm, xyz_s,
                                                            feat_s, xy_g, feat_g, N);

  // coarse visit lists only (fine grids go brick-LDS)
  hist_fused<<<dim3(pb, 8), 256, 0, stream>>>(xyz_s, xy_g, cnt_v, N);
  scan_blocksum<<<nbv, 256, 0, stream>>>(cnt_v, bsum, KVIS2);
  scan_write<<<nbv, 256, 0, stream>>>(cnt_v, bsum, cur_v, KVIS2);
  place_fused<<<dim3(pb, 8), 256, 0, stream>>>(xyz_s, xy_g, cur_v, visits, N);

  // creates
  create_block_fused<<<98304, 256, 0, stream>>>(feat_s, feat_g, cnt_v, cur_v, visits,
                                                grid);
  create_brick_fused<<<1792, 256, 0, stream>>>(xyz_s, feat_s, xy_g, feat_g, cnt_all,
                                               cur_all, grid, N);

  // fused encode: all 12 slots in one dispatch
  encode_all<<<(M * 32 + 255) / 256, 256, 0, stream>>>(xyz_i, grid, out, M);
}

// Round 19
// 776.824 us; speedup vs baseline: 1.6975x; 1.6975x over previous
//
#include <hip/hip_runtime.h>

#define NF 32
#define EPSF 1e-9f

// sort keyspace: [0,262144) morton3@64 ; [262144 + g*65536) pair g morton2@256
#define KSORT 458752
// coarse visit keyspace (visit lists only for coarse grids)
#define VO16 0
#define VO32 4096
#define VO64Q 36864
#define VO128Q 49152
#define KVIS2 98304
// grid layout (all 12 grids)
#define KO16 0
#define KO32 4096
#define KO64 36864
#define KO64Q 299008
#define KO128Q 311296
#define KO256Q 360448
#define KVIS 557056

__device__ __forceinline__ int cell_coord(float xv, int R, float& fr) {
  float x = xv * (float)(R - 1);
  int i0 = (int)floorf(x);
  i0 = min(max(i0, 0), R - 2);
  fr = x - (float)i0;
  return i0;
}
__device__ __forceinline__ float bf2f(unsigned short u) {
  return __uint_as_float((unsigned)u << 16);
}
__device__ __forceinline__ unsigned short f2bf(float x) {
  unsigned b = __float_as_uint(x);
  return (unsigned short)((b + 0x7FFF + ((b >> 16) & 1)) >> 16);
}
__device__ __forceinline__ unsigned p1b2(unsigned x) {
  x &= 0x3FF;
  x = (x | (x << 16)) & 0x030000FF;
  x = (x | (x << 8)) & 0x0300F00F;
  x = (x | (x << 4)) & 0x030C30C3;
  x = (x | (x << 2)) & 0x09249249;
  return x;
}
__device__ __forceinline__ unsigned p1b1(unsigned x) {
  x &= 0xFFFF;
  x = (x | (x << 8)) & 0x00FF00FF;
  x = (x | (x << 4)) & 0x0F0F0F0F;
  x = (x | (x << 2)) & 0x33333333;
  x = (x | (x << 1)) & 0x55555555;
  return x;
}
__device__ __forceinline__ unsigned c1b2(unsigned x) {
  x &= 0x09249249u;
  x = (x | (x >> 2)) & 0x030C30C3u;
  x = (x | (x >> 4)) & 0x0300F00Fu;
  x = (x | (x >> 8)) & 0x030000FFu;
  x = (x | (x >> 16)) & 0x3FFu;
  return x;
}
__device__ __forceinline__ unsigned c1b1(unsigned x) {
  x &= 0x55555555u;
  x = (x | (x >> 1)) & 0x33333333u;
  x = (x | (x >> 2)) & 0x0F0F0F0Fu;
  x = (x | (x >> 4)) & 0x00FF00FFu;
  x = (x | (x >> 8)) & 0xFFFFu;
  return x;
}

__device__ __forceinline__ int xcd_swz(int bid, int n) {
  return (bid & 7) * (n >> 3) + (bid >> 3);
}

// ---- wave-aggregated atomics over sorted-ish keys ----
__device__ __forceinline__ void agg_hist(int key, int* cnt) {
  int lane = threadIdx.x & 63;
  unsigned long long amask = __ballot(1);
  int nact = __popcll(amask);
  int prev = __shfl_up(key, 1);
  bool leader = (lane == 0) || (prev != key);
  unsigned long long lmask = __ballot(leader);
  if (leader) {
    unsigned long long above = (lane < 63) ? (lmask >> (lane + 1)) : 0ULL;
    int next = above ? (lane + 1 + (__ffsll((unsigned long long)above) - 1)) : nact;
    atomicAdd(&cnt[key], next - lane);
  }
}
template <int NC>
__device__ __forceinline__ void agg_place_batch(const int (&key)[NC], int* cur,
                                                int (&pos)[NC]) {
  int lane = threadIdx.x & 63;
  unsigned long long amask = __ballot(1);
  int nact = __popcll(amask);
  int ret[NC];
  int lp[NC];
#pragma unroll
  for (int c = 0; c < NC; ++c) {
    int prev = __shfl_up(key[c], 1);
    bool leader = (lane == 0) || (prev != key[c]);
    unsigned long long lmask = __ballot(leader);
    unsigned long long below = lmask & ((2ULL << lane) - 1ULL);
    lp[c] = 63 - __clzll((long long)below);
    ret[c] = 0;
    if (leader) {
      unsigned long long above = (lane < 63) ? (lmask >> (lane + 1)) : 0ULL;
      int next = above ? (lane + 1 + (__ffsll((unsigned long long)above) - 1)) : nact;
      ret[c] = atomicAdd(&cur[key[c]], next - lane);
    }
  }
#pragma unroll
  for (int c = 0; c < NC; ++c) pos[c] = __shfl(ret[c], lp[c]) + (lane - lp[c]);
}

// ---------------- fused sort keys: morton3@64 + 3 pair keys@256 ----------------
__global__ __launch_bounds__(256) void sort_hist_all(
    const float* __restrict__ xyz, int* __restrict__ cnt, int N) {
  int p = blockIdx.x * blockDim.x + threadIdx.x;
  if (p >= N) return;
  float fr;
  int c64[3], c256[3];
#pragma unroll
  for (int d = 0; d < 3; ++d) {
    c64[d] = cell_coord(xyz[p * 3 + d], 64, fr);
    c256[d] = cell_coord(xyz[p * 3 + d], 256, fr);
  }
  int k3 = (int)((p1b2((unsigned)c64[0]) << 2) | (p1b2((unsigned)c64[1]) << 1) |
                 p1b2((unsigned)c64[2]));
  atomicAdd(&cnt[k3], 1);
#pragma unroll
  for (int g = 0; g < 3; ++g) {
    int a = (g < 2) ? 0 : 1, b = (g == 0) ? 1 : 2;
    int key = 262144 + g * 65536 +
              (int)((p1b1((unsigned)c256[a]) << 1) | p1b1((unsigned)c256[b]));
    atomicAdd(&cnt[key], 1);
  }
}
__global__ __launch_bounds__(256) void sort_place_all(
    const float* __restrict__ xyz, int* __restrict__ cur, int* __restrict__ perm, int N) {
  int p = blockIdx.x * blockDim.x + threadIdx.x;
  if (p >= N) return;
  float fr;
  int c64[3], c256[3];
#pragma unroll
  for (int d = 0; d < 3; ++d) {
    c64[d] = cell_coord(xyz[p * 3 + d], 64, fr);
    c256[d] = cell_coord(xyz[p * 3 + d], 256, fr);
  }
  int k3 = (int)((p1b2((unsigned)c64[0]) << 2) | (p1b2((unsigned)c64[1]) << 1) |
                 p1b2((unsigned)c64[2]));
  perm[atomicAdd(&cur[k3], 1)] = p;
#pragma unroll
  for (int g = 0; g < 3; ++g) {
    int a = (g < 2) ? 0 : 1, b = (g == 0) ? 1 : 2;
    int key = 262144 + g * 65536 +
              (int)((p1b1((unsigned)c256[a]) << 1) | p1b1((unsigned)c256[b]));
    perm[atomicAdd(&cur[key], 1)] = p;
  }
}
__global__ __launch_bounds__(256) void permute_all(
    const float* __restrict__ xyz, const float* __restrict__ feat,
    const int* __restrict__ perm, float* __restrict__ xyz_s,
    unsigned short* __restrict__ feat_s, float* __restrict__ xy_g,
    unsigned short* __restrict__ feat_g, int N) {
  int t = blockIdx.x * blockDim.x + threadIdx.x;
  int s = t >> 5, f = t & 31;
  if (s >= 4 * N) return;
  int q = perm[s];
  float v = feat[(size_t)q * NF + f];
  if (s < N) {
    feat_s[(size_t)s * NF + f] = f2bf(v);
    if (f < 3) xyz_s[s * 3 + f] = xyz[q * 3 + f];
  } else {
    int sl = s - N;
    int g = sl / N;
    feat_g[(size_t)sl * NF + f] = f2bf(v);
    if (f < 2) {
      int a = (g < 2) ? 0 : 1, b = (g == 0) ? 1 : 2;
      xy_g[(size_t)sl * 2 + f] = xyz[q * 3 + (f == 0 ? a : b)];
    }
  }
}

// ---------------- scan (hierarchical, exclusive) ----------------
__global__ __launch_bounds__(256) void scan_blocksum(
    const int* __restrict__ cnt, int* __restrict__ bsum, int K) {
  __shared__ int red[256];
  int base = blockIdx.x * 2048 + threadIdx.x * 8;
  int s = 0;
#pragma unroll
  for (int j = 0; j < 8; ++j) {
    int k = base + j;
    if (k < K) s += cnt[k];
  }
  red[threadIdx.x] = s;
  __syncthreads();
  for (int off = 128; off > 0; off >>= 1) {
    if (threadIdx.x < off) red[threadIdx.x] += red[threadIdx.x + off];
    __syncthreads();
  }
  if (threadIdx.x == 0) bsum[blockIdx.x] = red[0];
}
__global__ __launch_bounds__(256) void scan_write(
    const int* __restrict__ cnt, const int* __restrict__ bsum,
    int* __restrict__ cur, int K) {
  __shared__ int lds[256];
  __shared__ int boff;
  int b = blockIdx.x, t = threadIdx.x;
  if (t == 0) {
    int s = 0;
    for (int j = 0; j < b; ++j) s += bsum[j];
    boff = s;
  }
  int base = b * 2048 + t * 8;
  int v[8];
  int s = 0;
#pragma unroll
  for (int j = 0; j < 8; ++j) {
    int k = base + j;
    v[j] = (k < K) ? cnt[k] : 0;
    s += v[j];
  }
  lds[t] = s;
  __syncthreads();
  for (int off = 1; off < 256; off <<= 1) {
    int add = (t >= off) ? lds[t - off] : 0;
    __syncthreads();
    lds[t] += add;
    __syncthreads();
  }
  int run = boff + lds[t] - s;
#pragma unroll
  for (int j = 0; j < 8; ++j) {
    int k = base + j;
    if (k < K) {
      cur[k] = run;
      run += v[j];
    }
  }
}

// ---------------- fused coarse hist: y=0..1 3D, y=2..7 2D(g,r) ----------------
__global__ __launch_bounds__(256) void hist_fused(
    const float* __restrict__ xyz_s, const float* __restrict__ xy_g,
    int* __restrict__ cnt, int N) {
  int y = blockIdx.y;
  int p = blockIdx.x * blockDim.x + threadIdx.x;
  if (p >= N) return;
  if (y < 2) {
    int R = 16 << y;
    int ko = (y == 0) ? VO16 : VO32;
    unsigned a0[3], a1[3];
    float fr[3];
#pragma unroll
    for (int d = 0; d < 3; ++d) {
      int i0 = cell_coord(xyz_s[p * 3 + d], R, fr[d]);
      a0[d] = p1b2((unsigned)i0);
      a1[d] = p1b2((unsigned)(i0 + 1));
    }
#pragma unroll
    for (int cb = 0; cb < 8; ++cb) {
      unsigned key = 0;
#pragma unroll
      for (int d = 0; d < 3; ++d) {
        int o = (cb >> d) & 1;
        key |= (o ? a1[d] : a0[d]) << (2 - d);
      }
      agg_hist(ko + (int)key, cnt);
    }
  } else {
    int idx = y - 2;
    int g = idx >> 1, r = idx & 1;
    int sl = g * N + p;
    int R = 64 << r;
    int kb = (r == 0) ? VO64Q : VO128Q;
    int base = kb + g * R * R;
    float frx, fry;
    int ix = cell_coord(xy_g[(size_t)sl * 2 + 0], R, frx);
    int iy = cell_coord(xy_g[(size_t)sl * 2 + 1], R, fry);
    unsigned ax0 = p1b1((unsigned)ix), ax1 = p1b1((unsigned)(ix + 1));
    unsigned ay0 = p1b1((unsigned)iy), ay1 = p1b1((unsigned)(iy + 1));
#pragma unroll
    for (int cb = 0; cb < 4; ++cb) {
      int o0 = (cb >> 1) & 1, o1 = cb & 1;
      agg_hist(base + (int)(((o0 ? ax1 : ax0) << 1) | (o1 ? ay1 : ay0)), cnt);
    }
  }
}

// ---------------- fused coarse placement (atomic): y=0..1 3D, y=2..7 2D ----------------
__global__ __launch_bounds__(256) void place_fused(
    const float* __restrict__ xyz_s, const float* __restrict__ xy_g,
    int* __restrict__ cur_v, int2* __restrict__ visits, int N) {
  int y = blockIdx.y;
  int p = blockIdx.x * blockDim.x + threadIdx.x;
  if (p >= N) return;
  if (y < 2) {
    int R = 16 << y;
    int ko = (y == 0) ? VO16 : VO32;
    unsigned a0[3], a1[3];
    float fr[3];
#pragma unroll
    for (int d = 0; d < 3; ++d) {
      int i0 = cell_coord(xyz_s[p * 3 + d], R, fr[d]);
      a0[d] = p1b2((unsigned)i0);
      a1[d] = p1b2((unsigned)(i0 + 1));
    }
    int keys[8];
    float ws[8];
#pragma unroll
    for (int cb = 0; cb < 8; ++cb) {
      float w = 1.f;
      unsigned key = 0;
#pragma unroll
      for (int d = 0; d < 3; ++d) {
        int o = (cb >> d) & 1;
        w *= o ? fr[d] : (1.f - fr[d]);
        key |= (o ? a1[d] : a0[d]) << (2 - d);
      }
      keys[cb] = ko + (int)key;
      ws[cb] = w;
    }
    int pos[8];
    agg_place_batch<8>(keys, cur_v, pos);
#pragma unroll
    for (int cb = 0; cb < 8; ++cb)
      visits[pos[cb]] = make_int2(p, __float_as_int(ws[cb]));
  } else {
    int idx = y - 2;
    int g = idx >> 1, r = idx & 1;
    int sl = g * N + p;
    int R = 64 << r;
    int kb = (r == 0) ? VO64Q : VO128Q;
    int base = kb + g * R * R;
    float frx, fry;
    int ix = cell_coord(xy_g[(size_t)sl * 2 + 0], R, frx);
    int iy = cell_coord(xy_g[(size_t)sl * 2 + 1], R, fry);
    unsigned ax0 = p1b1((unsigned)ix), ax1 = p1b1((unsigned)(ix + 1));
    unsigned ay0 = p1b1((unsigned)iy), ay1 = p1b1((unsigned)(iy + 1));
    int keys[4];
    float ws[4];
#pragma unroll
    for (int cb = 0; cb < 4; ++cb) {
      int o0 = (cb >> 1) & 1, o1 = cb & 1;
      ws[cb] = (o0 ? frx : 1.f - frx) * (o1 ? fry : 1.f - fry);
      keys[cb] = base + (int)(((o0 ? ax1 : ax0) << 1) | (o1 ? ay1 : ay0));
    }
    int pos[4];
    agg_place_batch<4>(keys, cur_v, pos);
#pragma unroll
    for (int cb = 0; cb < 4; ++cb)
      visits[pos[cb]] = make_int2(sl, __float_as_int(ws[cb]));
  }
}

// ---------------- stencil: per-cell (beg,cnt) neighbor tables (lane-parallel) ----------------
__global__ __launch_bounds__(256) void stencil_coff(
    const int* __restrict__ cnt_all, const int* __restrict__ cur_all,
    int2* __restrict__ ccoff3, int2* __restrict__ ccoff2, int N) {
  int t = blockIdx.x * 256 + threadIdx.x;  // < 458752
  if (t < 262144) {
    int c = t;
    int cx = (int)c1b2((unsigned)c >> 2), cy = (int)c1b2((unsigned)c >> 1),
        cz = (int)c1b2((unsigned)c);
#pragma unroll
    for (int cb = 0; cb < 8; ++cb) {
      int hx = cx - (cb & 1), hy = cy - ((cb >> 1) & 1), hz = cz - ((cb >> 2) & 1);
      int n = 0, b = 0;
      if (hx >= 0 && hy >= 0 && hz >= 0) {
        int hk = (int)((p1b2((unsigned)hx) << 2) | (p1b2((unsigned)hy) << 1) |
                       p1b2((unsigned)hz));
        n = cnt_all[hk];
        b = cur_all[hk] - n;
      }
      ccoff3[(size_t)c * 8 + cb] = make_int2(b, n);
    }
  } else {
    int t2 = t - 262144;
    int g = t2 >> 16, m = t2 & 65535;
    int cx = (int)c1b1((unsigned)m >> 1), cy = (int)c1b1((unsigned)m);
    const int* cntg = cnt_all + 262144 + g * 65536;
    const int* curg = cur_all + 262144 + g * 65536;
#pragma unroll
    for (int cb = 0; cb < 4; ++cb) {
      int hx = cx - ((cb >> 1) & 1), hy = cy - (cb & 1);
      int n = 0, b = 0;
      if (hx >= 0 && hy >= 0) {
        int hk = (int)((p1b1((unsigned)hx) << 1) | p1b1((unsigned)hy));
        n = cntg[hk];
        b = curg[hk] - n - N;  // index into xy_g/feat_g
      }
      ccoff2[(size_t)t2 * 4 + cb] = make_int2(b, n);
    }
  }
}

// ---------------- fused create: coarse visit-list + fine direct-gather in ONE dispatch ----------------
// bid < 98304: block-per-cell coarse segments; else: wave-per-cell direct (64^3, 256^2)
__global__ __launch_bounds__(256) void create_all_fused(
    const unsigned short* __restrict__ feat_s, const unsigned short* __restrict__ feat_g,
    const float* __restrict__ xyz_s, const float* __restrict__ xy_g,
    const int* __restrict__ cnt, const int* __restrict__ cur_end,
    const int2* __restrict__ visits, const int2* __restrict__ ccoff3,
    const int2* __restrict__ ccoff2, unsigned short* __restrict__ grid, int N) {
  __shared__ int2 vlds[1024];
  __shared__ float2 lacc[256];
  __shared__ float lw[16];
  int bid = blockIdx.x;
  if (bid < 98304) {
    // ---- coarse: block-per-cell over 4 segments ----
    int vo, go, base, nseg;
    const unsigned short* feat;
    if (bid < 4096) {
      vo = VO16; go = KO16; base = 0; nseg = 4096; feat = feat_s;
    } else if (bid < 36864) {
      vo = VO32; go = KO32; base = 4096; nseg = 32768; feat = feat_s;
    } else if (bid < 49152) {
      vo = VO64Q; go = KO64Q; base = 36864; nseg = 12288; feat = feat_g;
    } else {
      vo = VO128Q; go = KO128Q; base = 49152; nseg = 49152; feat = feat_g;
    }
    int idx = xcd_swz(bid - base, nseg);
    int vcell = vo + idx;
    int e = cur_end[vcell];
    int n = cnt[vcell];
    int beg = e - n;
    for (int i = threadIdx.x; i < n && i < 1024; i += 256) vlds[i] = visits[beg + i];
    __syncthreads();
    bool inl = (n <= 1024);
    int slot = threadIdx.x >> 4;
    int fp = threadIdx.x & 15;
    float2 acc = {0.f, 0.f};
    float wsum = 0.f;
    int i = slot;
    for (; i + 16 < n; i += 32) {
      int2 v0 = inl ? vlds[i] : visits[beg + i];
      int2 v1 = inl ? vlds[i + 16] : visits[beg + i + 16];
      unsigned u0 = *(const unsigned*)(feat + (size_t)v0.x * NF + 2 * fp);
      unsigned u1 = *(const unsigned*)(feat + (size_t)v1.x * NF + 2 * fp);
      float w0 = __int_as_float(v0.y), w1 = __int_as_float(v1.y);
      acc.x = fmaf(w0, bf2f((unsigned short)u0), acc.x);
      acc.y = fmaf(w0, bf2f((unsigned short)(u0 >> 16)), acc.y);
      acc.x = fmaf(w1, bf2f((unsigned short)u1), acc.x);
      acc.y = fmaf(w1, bf2f((unsigned short)(u1 >> 16)), acc.y);
      wsum += w0 + w1;
    }
    if (i < n) {
      int2 v = inl ? vlds[i] : visits[beg + i];
      unsigned u = *(const unsigned*)(feat + (size_t)v.x * NF + 2 * fp);
      float w = __int_as_float(v.y);
      acc.x = fmaf(w, bf2f((unsigned short)u), acc.x);
      acc.y = fmaf(w, bf2f((unsigned short)(u >> 16)), acc.y);
      wsum += w;
    }
    lacc[threadIdx.x] = acc;
    if (fp == 0) lw[slot] = wsum;
    __syncthreads();
    if (threadIdx.x < 16) {
      float2 a = {0.f, 0.f};
      float w = 0.f;
#pragma unroll
      for (int s = 0; s < 16; ++s) {
        float2 t2 = lacc[s * 16 + threadIdx.x];
        a.x += t2.x;
        a.y += t2.y;
        w += lw[s];
      }
      float inv = 1.f / fmaxf(w, EPSF);
      unsigned short lo = f2bf(a.x * inv), hi = f2bf(a.y * inv);
      *(unsigned*)(grid + (size_t)(go + idx) * NF + 2 * threadIdx.x) =
          (unsigned)lo | ((unsigned)hi << 16);
    }
    return;
  }
  // ---- fine: direct-gather, wave-per-cell (4/block) ----
  int dbid = bid - 98304;
  int wave = threadIdx.x >> 6, lane = threadIdx.x & 63;
  int slot = lane >> 4;
  int fp = lane & 15;
  int2* wl = vlds + wave * 256;
  float2 acc = {0.f, 0.f};
  float wsum = 0.f;
  int gcell;
  if (dbid < 65536) {
    int cell = xcd_swz(dbid, 65536) * 4 + wave;  // [0, 262144)
    gcell = KO64 + cell;
    int cx = (int)c1b2((unsigned)cell >> 2);
    int cy = (int)c1b2((unsigned)cell >> 1);
    int cz = (int)c1b2((unsigned)cell);
    int beg[8], pre[8];
    int tot = 0;
#pragma unroll
    for (int cb = 0; cb < 8; ++cb) {
      int2 co = ccoff3[(size_t)cell * 8 + cb];
      pre[cb] = tot;
      beg[cb] = co.x;
      tot += co.y;
    }
    for (int cbase = 0; cbase < tot; cbase += 256) {
      int chunk = min(tot - cbase, 256);
      for (int i = lane; i < chunk; i += 64) {
        int ii = cbase + i;
        int cls = 0, b = beg[0], p0 = pre[0];
#pragma unroll
        for (int c2 = 1; c2 < 8; ++c2)
          if (ii >= pre[c2]) { cls = c2; b = beg[c2]; p0 = pre[c2]; }
        int q = b + (ii - p0);
        int hx = cx - (cls & 1), hy = cy - ((cls >> 1) & 1), hz = cz - ((cls >> 2) & 1);
        float frx = xyz_s[q * 3 + 0] * 63.0f - (float)hx;
        float fry = xyz_s[q * 3 + 1] * 63.0f - (float)hy;
        float frz = xyz_s[q * 3 + 2] * 63.0f - (float)hz;
        float w = ((cls & 1) ? frx : 1.f - frx) *
                  (((cls >> 1) & 1) ? fry : 1.f - fry) *
                  (((cls >> 2) & 1) ? frz : 1.f - frz);
        wl[i] = make_int2(q, __float_as_int(w));
      }
      for (int i = slot; i < chunk; i += 4) {
        int2 v = wl[i];
        unsigned u = *(const unsigned*)(feat_s + (size_t)v.x * NF + 2 * fp);
        float w = __int_as_float(v.y);
        acc.x = fmaf(w, bf2f((unsigned short)u), acc.x);
        acc.y = fmaf(w, bf2f((unsigned short)(u >> 16)), acc.y);
        wsum += w;
      }
    }
  } else {
    int cl = xcd_swz(dbid - 65536, 49152) * 4 + wave;  // [0, 196608)
    gcell = KO256Q + cl;
    int g = cl >> 16, m = cl & 65535;
    int cx = (int)c1b1((unsigned)m >> 1);
    int cy = (int)c1b1((unsigned)m);
    int beg[4], pre[4];
    int tot = 0;
#pragma unroll
    for (int cb = 0; cb < 4; ++cb) {
      int2 co = ccoff2[(size_t)cl * 4 + cb];
      pre[cb] = tot;
      beg[cb] = co.x;
      tot += co.y;
    }
    for (int cbase = 0; cbase < tot; cbase += 256) {
      int chunk = min(tot - cbase, 256);
      for (int i = lane; i < chunk; i += 64) {
        int ii = cbase + i;
        int cls = 0, b = beg[0], p0 = pre[0];
#pragma unroll
        for (int c2 = 1; c2 < 4; ++c2)
          if (ii >= pre[c2]) { cls = c2; b = beg[c2]; p0 = pre[c2]; }
        int q = b + (ii - p0);
        int hx = cx - ((cls >> 1) & 1), hy = cy - (cls & 1);
        float frx = xy_g[(size_t)q * 2 + 0] * 255.0f - (float)hx;
        float fry = xy_g[(size_t)q * 2 + 1] * 255.0f - (float)hy;
        float w = (((cls >> 1) & 1) ? frx : 1.f - frx) * ((cls & 1) ? fry : 1.f - fry);
        wl[i] = make_int2(q, __float_as_int(w));
      }
      for (int i = slot; i < chunk; i += 4) {
        int2 v = wl[i];
        unsigned u = *(const unsigned*)(feat_g + (size_t)v.x * NF + 2 * fp);
        float w = __int_as_float(v.y);
        acc.x = fmaf(w, bf2f((unsigned short)u), acc.x);
        acc.y = fmaf(w, bf2f((unsigned short)(u >> 16)), acc.y);
        wsum += w;
      }
    }
  }
  acc.x += __shfl_xor(acc.x, 16);
  acc.y += __shfl_xor(acc.y, 16);
  wsum += __shfl_xor(wsum, 16);
  acc.x += __shfl_xor(acc.x, 32);
  acc.y += __shfl_xor(acc.y, 32);
  wsum += __shfl_xor(wsum, 32);
  if (slot == 0) {
    float inv = 1.f / fmaxf(wsum, EPSF);
    unsigned short lo = f2bf(acc.x * inv), hi = f2bf(acc.y * inv);
    *(unsigned*)(grid + (size_t)gcell * NF + 2 * fp) =
        (unsigned)lo | ((unsigned)hi << 16);
  }
}

// ---------------- fused encode: all 12 slots ----------------
__global__ __launch_bounds__(256) void encode_all(
    const float* __restrict__ xyz, const unsigned short* __restrict__ grid,
    float* __restrict__ out, int M) {
  int t = blockIdx.x * blockDim.x + threadIdx.x;
  int m = t >> 5, f = t & 31;
  if (m >= M) return;
  float X[3];
#pragma unroll
  for (int d = 0; d < 3; ++d) X[d] = xyz[m * 3 + d];
  {
    const int RS[3] = {16, 32, 64};
    const int KO[3] = {KO16, KO32, KO64};
#pragma unroll
    for (int r = 0; r < 3; ++r) {
      unsigned a0[3], a1[3];
      float fr[3];
#pragma unroll
      for (int d = 0; d < 3; ++d) {
        int i0 = cell_coord(X[d], RS[r], fr[d]);
        a0[d] = p1b2((unsigned)i0);
        a1[d] = p1b2((unsigned)(i0 + 1));
      }
      float acc = 0.f;
#pragma unroll
      for (int cb = 0; cb < 8; ++cb) {
        float w = 1.f;
        unsigned key = 0;
#pragma unroll
        for (int d = 0; d < 3; ++d) {
          int o = (cb >> d) & 1;
          w *= o ? fr[d] : (1.f - fr[d]);
          key |= (o ? a1[d] : a0[d]) << (2 - d);
        }
        acc = fmaf(w, bf2f(grid[(size_t)(KO[r] + (int)key) * NF + f]), acc);
      }
      out[(size_t)m * 384 + r * 32 + f] = acc;
    }
  }
  {
    const int RS[3] = {64, 128, 256};
    const int KB[3] = {KO64Q, KO128Q, KO256Q};
    const int RSQ[3] = {4096, 16384, 65536};
#pragma unroll
    for (int r = 0; r < 3; ++r) {
      unsigned b0[3], b1[3];
      float fr[3];
#pragma unroll
      for (int d = 0; d < 3; ++d) {
        int i0 = cell_coord(X[d], RS[r], fr[d]);
        b0[d] = p1b1((unsigned)i0);
        b1[d] = p1b1((unsigned)(i0 + 1));
      }
#pragma unroll
      for (int g = 0; g < 3; ++g) {
        int a = (g < 2) ? 0 : 1, b = (g == 0) ? 1 : 2;
        int base = KB[r] + g * RSQ[r];
        float acc = 0.f;
#pragma unroll
        for (int cb = 0; cb < 4; ++cb) {
          int o0 = (cb >> 1) & 1, o1 = cb & 1;
          float w = (o0 ? fr[a] : 1.f - fr[a]) * (o1 ? fr[b] : 1.f - fr[b]);
          int k = base + (int)(((o0 ? b1[a] : b0[a]) << 1) | (o1 ? b1[b] : b0[b]));
          acc = fmaf(w, bf2f(grid[(size_t)k * NF + f]), acc);
        }
        out[(size_t)m * 384 + (3 + g * 3 + r) * 32 + f] = acc;
      }
    }
  }
}

extern "C" void kernel_launch(void* const* d_in, const int* in_sizes, int n_in,
                              void* d_out, int out_size, void* d_ws, size_t ws_size,
                              hipStream_t stream) {
  const float* xyz_c = (const float*)d_in[0];
  const float* xyz_i = (const float*)d_in[1];
  const float* feat = (const float*)d_in[2];
  float* out = (float*)d_out;
  int N = in_sizes[0] / 3;
  int M = in_sizes[1] / 3;

  char* wsb = (char*)d_ws;
  size_t off = 0;
  auto al = [&](size_t bytes) {
    size_t o = off;
    off = (off + bytes + 255) & ~(size_t)255;
    return wsb + o;
  };
  const int KALL = KSORT + KVIS2;
  int* cnt_all = (int*)al((size_t)KALL * 4);
  int* cur_all = (int*)al((size_t)KALL * 4);
  int* bsum = (int*)al(4096);
  int* perm = (int*)al((size_t)4 * N * 4);
  float* xyz_s = (float*)al((size_t)N * 3 * 4);
  unsigned short* feat_s = (unsigned short*)al((size_t)N * NF * 2);
  float* xy_g = (float*)al((size_t)3 * N * 2 * 4);
  unsigned short* feat_g = (unsigned short*)al((size_t)3 * N * NF * 2);
  int2* visits = (int2*)al((size_t)40 * N * 8);
  unsigned short* grid = (unsigned short*)al((size_t)KVIS * NF * 2);
  int2* ccoff3 = (int2*)al((size_t)262144 * 8 * 8);
  int2* ccoff2 = (int2*)al((size_t)196608 * 4 * 8);

  int* cnt_v = cnt_all + KSORT;
  int* cur_v = cur_all + KSORT;

  int pb = (N + 255) / 256;
  int nbs = (KSORT + 2047) / 2048;
  int nbv = (KVIS2 + 2047) / 2048;

  hipMemsetAsync(cnt_all, 0, (size_t)KALL * 4, stream);

  // fused sort of all 4 point-orderings
  sort_hist_all<<<pb, 256, 0, stream>>>(xyz_c, cnt_all, N);
  scan_blocksum<<<nbs, 256, 0, stream>>>(cnt_all, bsum, KSORT);
  scan_write<<<nbs, 256, 0, stream>>>(cnt_all, bsum, cur_all, KSORT);
  sort_place_all<<<pb, 256, 0, stream>>>(xyz_c, cur_all, perm, N);
  permute_all<<<(4 * N * 32 + 255) / 256, 256, 0, stream>>>(xyz_c, feat, perm, xyz_s,
                                                            feat_s, xy_g, feat_g, N);

  // neighbor tables for fine grids (lane-parallel)
  stencil_coff<<<KSORT / 256, 256, 0, stream>>>(cnt_all, cur_all, ccoff3, ccoff2, N);

  // coarse visit lists only (fine grids go direct-gather)
  hist_fused<<<dim3(pb, 8), 256, 0, stream>>>(xyz_s, xy_g, cnt_v, N);
  scan_blocksum<<<nbv, 256, 0, stream>>>(cnt_v, bsum, KVIS2);
  scan_write<<<nbv, 256, 0, stream>>>(cnt_v, bsum, cur_v, KVIS2);
  place_fused<<<dim3(pb, 8), 256, 0, stream>>>(xyz_s, xy_g, cur_v, visits, N);

  // single fused create: coarse (98304 blocks) + fine direct (114688 blocks)
  create_all_fused<<<98304 + 114688, 256, 0, stream>>>(
      feat_s, feat_g, xyz_s, xy_g, cnt_v, cur_v, visits, ccoff3, ccoff2, grid, N);

  // fused encode: all 12 slots in one dispatch
  encode_all<<<(M * 32 + 255) / 256, 256, 0, stream>>>(xyz_i, grid, out, M);
}

// Round 20
// 762.480 us; speedup vs baseline: 1.7294x; 1.0188x over previous
//
#include <hip/hip_runtime.h>

#define NF 32
#define EPSF 1e-9f

// sort keyspace: [0,262144) morton3@64 ; [262144 + g*65536) pair g morton2@256
#define KSORT 458752
// coarse visit keyspace (visit lists only for coarse grids)
#define VO16 0
#define VO32 4096
#define VO64Q 36864
#define VO128Q 49152
#define KVIS2 98304
// grid layout (all 12 grids)
#define KO16 0
#define KO32 4096
#define KO64 36864
#define KO64Q 299008
#define KO128Q 311296
#define KO256Q 360448
#define KVIS 557056

__device__ __forceinline__ int cell_coord(float xv, int R, float& fr) {
  float x = xv * (float)(R - 1);
  int i0 = (int)floorf(x);
  i0 = min(max(i0, 0), R - 2);
  fr = x - (float)i0;
  return i0;
}
__device__ __forceinline__ float bf2f(unsigned short u) {
  return __uint_as_float((unsigned)u << 16);
}
__device__ __forceinline__ unsigned short f2bf(float x) {
  unsigned b = __float_as_uint(x);
  return (unsigned short)((b + 0x7FFF + ((b >> 16) & 1)) >> 16);
}
__device__ __forceinline__ unsigned p1b2(unsigned x) {
  x &= 0x3FF;
  x = (x | (x << 16)) & 0x030000FF;
  x = (x | (x << 8)) & 0x0300F00F;
  x = (x | (x << 4)) & 0x030C30C3;
  x = (x | (x << 2)) & 0x09249249;
  return x;
}
__device__ __forceinline__ unsigned p1b1(unsigned x) {
  x &= 0xFFFF;
  x = (x | (x << 8)) & 0x00FF00FF;
  x = (x | (x << 4)) & 0x0F0F0F0F;
  x = (x | (x << 2)) & 0x33333333;
  x = (x | (x << 1)) & 0x55555555;
  return x;
}
__device__ __forceinline__ unsigned c1b2(unsigned x) {
  x &= 0x09249249u;
  x = (x | (x >> 2)) & 0x030C30C3u;
  x = (x | (x >> 4)) & 0x0300F00Fu;
  x = (x | (x >> 8)) & 0x030000FFu;
  x = (x | (x >> 16)) & 0x3FFu;
  return x;
}
__device__ __forceinline__ unsigned c1b1(unsigned x) {
  x &= 0x55555555u;
  x = (x | (x >> 1)) & 0x33333333u;
  x = (x | (x >> 2)) & 0x0F0F0F0Fu;
  x = (x | (x >> 4)) & 0x00FF00FFu;
  x = (x | (x >> 8)) & 0xFFFFu;
  return x;
}

__device__ __forceinline__ int xcd_swz(int bid, int n) {
  return (bid & 7) * (n >> 3) + (bid >> 3);
}

// ---- wave-aggregated atomics over sorted-ish keys ----
__device__ __forceinline__ void agg_hist(int key, int* cnt) {
  int lane = threadIdx.x & 63;
  unsigned long long amask = __ballot(1);
  int nact = __popcll(amask);
  int prev = __shfl_up(key, 1);
  bool leader = (lane == 0) || (prev != key);
  unsigned long long lmask = __ballot(leader);
  if (leader) {
    unsigned long long above = (lane < 63) ? (lmask >> (lane + 1)) : 0ULL;
    int next = above ? (lane + 1 + (__ffsll((unsigned long long)above) - 1)) : nact;
    atomicAdd(&cnt[key], next - lane);
  }
}
template <int NC>
__device__ __forceinline__ void agg_place_batch(const int (&key)[NC], int* cur,
                                                int (&pos)[NC]) {
  int lane = threadIdx.x & 63;
  unsigned long long amask = __ballot(1);
  int nact = __popcll(amask);
  int ret[NC];
  int lp[NC];
#pragma unroll
  for (int c = 0; c < NC; ++c) {
    int prev = __shfl_up(key[c], 1);
    bool leader = (lane == 0) || (prev != key[c]);
    unsigned long long lmask = __ballot(leader);
    unsigned long long below = lmask & ((2ULL << lane) - 1ULL);
    lp[c] = 63 - __clzll((long long)below);
    ret[c] = 0;
    if (leader) {
      unsigned long long above = (lane < 63) ? (lmask >> (lane + 1)) : 0ULL;
      int next = above ? (lane + 1 + (__ffsll((unsigned long long)above) - 1)) : nact;
      ret[c] = atomicAdd(&cur[key[c]], next - lane);
    }
  }
#pragma unroll
  for (int c = 0; c < NC; ++c) pos[c] = __shfl(ret[c], lp[c]) + (lane - lp[c]);
}

// ---------------- fused sort keys: morton3@64 + 3 pair keys@256 ----------------
__global__ __launch_bounds__(256) void sort_hist_all(
    const float* __restrict__ xyz, int* __restrict__ cnt, int N) {
  int p = blockIdx.x * blockDim.x + threadIdx.x;
  if (p >= N) return;
  float fr;
  int c64[3], c256[3];
#pragma unroll
  for (int d = 0; d < 3; ++d) {
    c64[d] = cell_coord(xyz[p * 3 + d], 64, fr);
    c256[d] = cell_coord(xyz[p * 3 + d], 256, fr);
  }
  int k3 = (int)((p1b2((unsigned)c64[0]) << 2) | (p1b2((unsigned)c64[1]) << 1) |
                 p1b2((unsigned)c64[2]));
  atomicAdd(&cnt[k3], 1);
#pragma unroll
  for (int g = 0; g < 3; ++g) {
    int a = (g < 2) ? 0 : 1, b = (g == 0) ? 1 : 2;
    int key = 262144 + g * 65536 +
              (int)((p1b1((unsigned)c256[a]) << 1) | p1b1((unsigned)c256[b]));
    atomicAdd(&cnt[key], 1);
  }
}
__global__ __launch_bounds__(256) void sort_place_all(
    const float* __restrict__ xyz, int* __restrict__ cur, int* __restrict__ perm, int N) {
  int p = blockIdx.x * blockDim.x + threadIdx.x;
  if (p >= N) return;
  float fr;
  int c64[3], c256[3];
#pragma unroll
  for (int d = 0; d < 3; ++d) {
    c64[d] = cell_coord(xyz[p * 3 + d], 64, fr);
    c256[d] = cell_coord(xyz[p * 3 + d], 256, fr);
  }
  int k3 = (int)((p1b2((unsigned)c64[0]) << 2) | (p1b2((unsigned)c64[1]) << 1) |
                 p1b2((unsigned)c64[2]));
  perm[atomicAdd(&cur[k3], 1)] = p;
#pragma unroll
  for (int g = 0; g < 3; ++g) {
    int a = (g < 2) ? 0 : 1, b = (g == 0) ? 1 : 2;
    int key = 262144 + g * 65536 +
              (int)((p1b1((unsigned)c256[a]) << 1) | p1b1((unsigned)c256[b]));
    perm[atomicAdd(&cur[key], 1)] = p;
  }
}
__global__ __launch_bounds__(256) void permute_all(
    const float* __restrict__ xyz, const float* __restrict__ feat,
    const int* __restrict__ perm, float* __restrict__ xyz_s,
    unsigned short* __restrict__ feat_s, float* __restrict__ xy_g,
    unsigned short* __restrict__ feat_g, int N) {
  int t = blockIdx.x * blockDim.x + threadIdx.x;
  int s = t >> 5, f = t & 31;
  if (s >= 4 * N) return;
  int q = perm[s];
  float v = feat[(size_t)q * NF + f];
  if (s < N) {
    feat_s[(size_t)s * NF + f] = f2bf(v);
    if (f < 3) xyz_s[s * 3 + f] = xyz[q * 3 + f];
  } else {
    int sl = s - N;
    int g = sl / N;
    feat_g[(size_t)sl * NF + f] = f2bf(v);
    if (f < 2) {
      int a = (g < 2) ? 0 : 1, b = (g == 0) ? 1 : 2;
      xy_g[(size_t)sl * 2 + f] = xyz[q * 3 + (f == 0 ? a : b)];
    }
  }
}

// ---------------- scan (hierarchical, exclusive) ----------------
__global__ __launch_bounds__(256) void scan_blocksum(
    const int* __restrict__ cnt, int* __restrict__ bsum, int K) {
  __shared__ int red[256];
  int base = blockIdx.x * 2048 + threadIdx.x * 8;
  int s = 0;
#pragma unroll
  for (int j = 0; j < 8; ++j) {
    int k = base + j;
    if (k < K) s += cnt[k];
  }
  red[threadIdx.x] = s;
  __syncthreads();
  for (int off = 128; off > 0; off >>= 1) {
    if (threadIdx.x < off) red[threadIdx.x] += red[threadIdx.x + off];
    __syncthreads();
  }
  if (threadIdx.x == 0) bsum[blockIdx.x] = red[0];
}
__global__ __launch_bounds__(256) void scan_write(
    const int* __restrict__ cnt, const int* __restrict__ bsum,
    int* __restrict__ cur, int K) {
  __shared__ int lds[256];
  __shared__ int boff;
  int b = blockIdx.x, t = threadIdx.x;
  if (t == 0) {
    int s = 0;
    for (int j = 0; j < b; ++j) s += bsum[j];
    boff = s;
  }
  int base = b * 2048 + t * 8;
  int v[8];
  int s = 0;
#pragma unroll
  for (int j = 0; j < 8; ++j) {
    int k = base + j;
    v[j] = (k < K) ? cnt[k] : 0;
    s += v[j];
  }
  lds[t] = s;
  __syncthreads();
  for (int off = 1; off < 256; off <<= 1) {
    int add = (t >= off) ? lds[t - off] : 0;
    __syncthreads();
    lds[t] += add;
    __syncthreads();
  }
  int run = boff + lds[t] - s;
#pragma unroll
  for (int j = 0; j < 8; ++j) {
    int k = base + j;
    if (k < K) {
      cur[k] = run;
      run += v[j];
    }
  }
}

// ---------------- fused coarse hist: y=0..1 3D, y=2..7 2D(g,r) ----------------
__global__ __launch_bounds__(256) void hist_fused(
    const float* __restrict__ xyz_s, const float* __restrict__ xy_g,
    int* __restrict__ cnt, int N) {
  int y = blockIdx.y;
  int p = blockIdx.x * blockDim.x + threadIdx.x;
  if (p >= N) return;
  if (y < 2) {
    int R = 16 << y;
    int ko = (y == 0) ? VO16 : VO32;
    unsigned a0[3], a1[3];
    float fr[3];
#pragma unroll
    for (int d = 0; d < 3; ++d) {
      int i0 = cell_coord(xyz_s[p * 3 + d], R, fr[d]);
      a0[d] = p1b2((unsigned)i0);
      a1[d] = p1b2((unsigned)(i0 + 1));
    }
#pragma unroll
    for (int cb = 0; cb < 8; ++cb) {
      unsigned key = 0;
#pragma unroll
      for (int d = 0; d < 3; ++d) {
        int o = (cb >> d) & 1;
        key |= (o ? a1[d] : a0[d]) << (2 - d);
      }
      agg_hist(ko + (int)key, cnt);
    }
  } else {
    int idx = y - 2;
    int g = idx >> 1, r = idx & 1;
    int sl = g * N + p;
    int R = 64 << r;
    int kb = (r == 0) ? VO64Q : VO128Q;
    int base = kb + g * R * R;
    float frx, fry;
    int ix = cell_coord(xy_g[(size_t)sl * 2 + 0], R, frx);
    int iy = cell_coord(xy_g[(size_t)sl * 2 + 1], R, fry);
    unsigned ax0 = p1b1((unsigned)ix), ax1 = p1b1((unsigned)(ix + 1));
    unsigned ay0 = p1b1((unsigned)iy), ay1 = p1b1((unsigned)(iy + 1));
#pragma unroll
    for (int cb = 0; cb < 4; ++cb) {
      int o0 = (cb >> 1) & 1, o1 = cb & 1;
      agg_hist(base + (int)(((o0 ? ax1 : ax0) << 1) | (o1 ? ay1 : ay0)), cnt);
    }
  }
}

// ---------------- fused coarse placement (atomic): y=0..1 3D, y=2..7 2D ----------------
__global__ __launch_bounds__(256) void place_fused(
    const float* __restrict__ xyz_s, const float* __restrict__ xy_g,
    int* __restrict__ cur_v, int2* __restrict__ visits, int N) {
  int y = blockIdx.y;
  int p = blockIdx.x * blockDim.x + threadIdx.x;
  if (p >= N) return;
  if (y < 2) {
    int R = 16 << y;
    int ko = (y == 0) ? VO16 : VO32;
    unsigned a0[3], a1[3];
    float fr[3];
#pragma unroll
    for (int d = 0; d < 3; ++d) {
      int i0 = cell_coord(xyz_s[p * 3 + d], R, fr[d]);
      a0[d] = p1b2((unsigned)i0);
      a1[d] = p1b2((unsigned)(i0 + 1));
    }
    int keys[8];
    float ws[8];
#pragma unroll
    for (int cb = 0; cb < 8; ++cb) {
      float w = 1.f;
      unsigned key = 0;
#pragma unroll
      for (int d = 0; d < 3; ++d) {
        int o = (cb >> d) & 1;
        w *= o ? fr[d] : (1.f - fr[d]);
        key |= (o ? a1[d] : a0[d]) << (2 - d);
      }
      keys[cb] = ko + (int)key;
      ws[cb] = w;
    }
    int pos[8];
    agg_place_batch<8>(keys, cur_v, pos);
#pragma unroll
    for (int cb = 0; cb < 8; ++cb)
      visits[pos[cb]] = make_int2(p, __float_as_int(ws[cb]));
  } else {
    int idx = y - 2;
    int g = idx >> 1, r = idx & 1;
    int sl = g * N + p;
    int R = 64 << r;
    int kb = (r == 0) ? VO64Q : VO128Q;
    int base = kb + g * R * R;
    float frx, fry;
    int ix = cell_coord(xy_g[(size_t)sl * 2 + 0], R, frx);
    int iy = cell_coord(xy_g[(size_t)sl * 2 + 1], R, fry);
    unsigned ax0 = p1b1((unsigned)ix), ax1 = p1b1((unsigned)(ix + 1));
    unsigned ay0 = p1b1((unsigned)iy), ay1 = p1b1((unsigned)(iy + 1));
    int keys[4];
    float ws[4];
#pragma unroll
    for (int cb = 0; cb < 4; ++cb) {
      int o0 = (cb >> 1) & 1, o1 = cb & 1;
      ws[cb] = (o0 ? frx : 1.f - frx) * (o1 ? fry : 1.f - fry);
      keys[cb] = base + (int)(((o0 ? ax1 : ax0) << 1) | (o1 ? ay1 : ay0));
    }
    int pos[4];
    agg_place_batch<4>(keys, cur_v, pos);
#pragma unroll
    for (int cb = 0; cb < 4; ++cb)
      visits[pos[cb]] = make_int2(sl, __float_as_int(ws[cb]));
  }
}

// ---------------- stencil: per-cell (beg,cnt) neighbor tables (lane-parallel) ----------------
__global__ __launch_bounds__(256) void stencil_coff(
    const int* __restrict__ cnt_all, const int* __restrict__ cur_all,
    int2* __restrict__ ccoff3, int2* __restrict__ ccoff2, int N) {
  int t = blockIdx.x * 256 + threadIdx.x;  // < 458752
  if (t < 262144) {
    int c = t;
    int cx = (int)c1b2((unsigned)c >> 2), cy = (int)c1b2((unsigned)c >> 1),
        cz = (int)c1b2((unsigned)c);
#pragma unroll
    for (int cb = 0; cb < 8; ++cb) {
      int hx = cx - (cb & 1), hy = cy - ((cb >> 1) & 1), hz = cz - ((cb >> 2) & 1);
      int n = 0, b = 0;
      if (hx >= 0 && hy >= 0 && hz >= 0) {
        int hk = (int)((p1b2((unsigned)hx) << 2) | (p1b2((unsigned)hy) << 1) |
                       p1b2((unsigned)hz));
        n = cnt_all[hk];
        b = cur_all[hk] - n;
      }
      ccoff3[(size_t)c * 8 + cb] = make_int2(b, n);
    }
  } else {
    int t2 = t - 262144;
    int g = t2 >> 16, m = t2 & 65535;
    int cx = (int)c1b1((unsigned)m >> 1), cy = (int)c1b1((unsigned)m);
    const int* cntg = cnt_all + 262144 + g * 65536;
    const int* curg = cur_all + 262144 + g * 65536;
#pragma unroll
    for (int cb = 0; cb < 4; ++cb) {
      int hx = cx - ((cb >> 1) & 1), hy = cy - (cb & 1);
      int n = 0, b = 0;
      if (hx >= 0 && hy >= 0) {
        int hk = (int)((p1b1((unsigned)hx) << 1) | p1b1((unsigned)hy));
        n = cntg[hk];
        b = curg[hk] - n - N;  // index into xy_g/feat_g
      }
      ccoff2[(size_t)t2 * 4 + cb] = make_int2(b, n);
    }
  }
}

// ---------------- fused create: coarse visit-list + fine direct-gather, ushort4 loads ----------------
// bid < 98304: block-per-cell coarse; else wave-per-cell direct (64^3, 256^2)
__global__ __launch_bounds__(256) void create_all_fused(
    const unsigned short* __restrict__ feat_s, const unsigned short* __restrict__ feat_g,
    const float* __restrict__ xyz_s, const float* __restrict__ xy_g,
    const int* __restrict__ cnt, const int* __restrict__ cur_end,
    const int2* __restrict__ visits, const int2* __restrict__ ccoff3,
    const int2* __restrict__ ccoff2, unsigned short* __restrict__ grid, int N) {
  __shared__ int2 vlds[1024];
  __shared__ float4 lacc4[256];
  __shared__ float lw[32];
  int bid = blockIdx.x;
  if (bid < 98304) {
    // ---- coarse: block-per-cell, 32 slots x 8 feature-quads ----
    int vo, go, base, nseg;
    const unsigned short* feat;
    if (bid < 4096) {
      vo = VO16; go = KO16; base = 0; nseg = 4096; feat = feat_s;
    } else if (bid < 36864) {
      vo = VO32; go = KO32; base = 4096; nseg = 32768; feat = feat_s;
    } else if (bid < 49152) {
      vo = VO64Q; go = KO64Q; base = 36864; nseg = 12288; feat = feat_g;
    } else {
      vo = VO128Q; go = KO128Q; base = 49152; nseg = 49152; feat = feat_g;
    }
    int idx = xcd_swz(bid - base, nseg);
    int vcell = vo + idx;
    int e = cur_end[vcell];
    int n = cnt[vcell];
    int beg = e - n;
    for (int i = threadIdx.x; i < n && i < 1024; i += 256) vlds[i] = visits[beg + i];
    __syncthreads();
    bool inl = (n <= 1024);
    int slot = threadIdx.x >> 3;  // 0..31
    int fq = threadIdx.x & 7;     // feature quad
    float4 acc = {0.f, 0.f, 0.f, 0.f};
    float wsum = 0.f;
    int i = slot;
    for (; i + 32 < n; i += 64) {
      int2 v0 = inl ? vlds[i] : visits[beg + i];
      int2 v1 = inl ? vlds[i + 32] : visits[beg + i + 32];
      uint2 u0 = *(const uint2*)(feat + (size_t)v0.x * NF + 4 * fq);
      uint2 u1 = *(const uint2*)(feat + (size_t)v1.x * NF + 4 * fq);
      float w0 = __int_as_float(v0.y), w1 = __int_as_float(v1.y);
      acc.x = fmaf(w0, bf2f((unsigned short)u0.x), acc.x);
      acc.y = fmaf(w0, bf2f((unsigned short)(u0.x >> 16)), acc.y);
      acc.z = fmaf(w0, bf2f((unsigned short)u0.y), acc.z);
      acc.w = fmaf(w0, bf2f((unsigned short)(u0.y >> 16)), acc.w);
      acc.x = fmaf(w1, bf2f((unsigned short)u1.x), acc.x);
      acc.y = fmaf(w1, bf2f((unsigned short)(u1.x >> 16)), acc.y);
      acc.z = fmaf(w1, bf2f((unsigned short)u1.y), acc.z);
      acc.w = fmaf(w1, bf2f((unsigned short)(u1.y >> 16)), acc.w);
      wsum += w0 + w1;
    }
    if (i < n) {
      int2 v = inl ? vlds[i] : visits[beg + i];
      uint2 u = *(const uint2*)(feat + (size_t)v.x * NF + 4 * fq);
      float w = __int_as_float(v.y);
      acc.x = fmaf(w, bf2f((unsigned short)u.x), acc.x);
      acc.y = fmaf(w, bf2f((unsigned short)(u.x >> 16)), acc.y);
      acc.z = fmaf(w, bf2f((unsigned short)u.y), acc.z);
      acc.w = fmaf(w, bf2f((unsigned short)(u.y >> 16)), acc.w);
      wsum += w;
    }
    lacc4[threadIdx.x] = acc;
    if (fq == 0) lw[slot] = wsum;
    __syncthreads();
    if (threadIdx.x < 8) {
      float4 a = {0.f, 0.f, 0.f, 0.f};
      float w = 0.f;
#pragma unroll
      for (int s = 0; s < 32; ++s) {
        float4 t2 = lacc4[s * 8 + threadIdx.x];
        a.x += t2.x;
        a.y += t2.y;
        a.z += t2.z;
        a.w += t2.w;
        w += lw[s];
      }
      float inv = 1.f / fmaxf(w, EPSF);
      uint2 o;
      o.x = (unsigned)f2bf(a.x * inv) | ((unsigned)f2bf(a.y * inv) << 16);
      o.y = (unsigned)f2bf(a.z * inv) | ((unsigned)f2bf(a.w * inv) << 16);
      *(uint2*)(grid + (size_t)(go + idx) * NF + 4 * threadIdx.x) = o;
    }
    return;
  }
  // ---- fine: direct-gather, wave-per-cell (4/block), 8 slots x 8 fq ----
  int dbid = bid - 98304;
  int wave = threadIdx.x >> 6, lane = threadIdx.x & 63;
  int slot = lane >> 3;  // 0..7
  int fq = lane & 7;
  int2* wl = vlds + wave * 256;
  float4 acc = {0.f, 0.f, 0.f, 0.f};
  float wsum = 0.f;
  int gcell;
  const unsigned short* featp;
  if (dbid < 65536) {
    int cell = xcd_swz(dbid, 65536) * 4 + wave;  // [0, 262144)
    gcell = KO64 + cell;
    featp = feat_s;
    int cx = (int)c1b2((unsigned)cell >> 2);
    int cy = (int)c1b2((unsigned)cell >> 1);
    int cz = (int)c1b2((unsigned)cell);
    int beg[8], pre[8];
    int tot = 0;
#pragma unroll
    for (int cb = 0; cb < 8; ++cb) {
      int2 co = ccoff3[(size_t)cell * 8 + cb];
      pre[cb] = tot;
      beg[cb] = co.x;
      tot += co.y;
    }
    for (int cbase = 0; cbase < tot; cbase += 256) {
      int chunk = min(tot - cbase, 256);
      for (int i = lane; i < chunk; i += 64) {
        int ii = cbase + i;
        int cls = 0, b = beg[0], p0 = pre[0];
#pragma unroll
        for (int c2 = 1; c2 < 8; ++c2)
          if (ii >= pre[c2]) { cls = c2; b = beg[c2]; p0 = pre[c2]; }
        int q = b + (ii - p0);
        int hx = cx - (cls & 1), hy = cy - ((cls >> 1) & 1), hz = cz - ((cls >> 2) & 1);
        float frx = xyz_s[q * 3 + 0] * 63.0f - (float)hx;
        float fry = xyz_s[q * 3 + 1] * 63.0f - (float)hy;
        float frz = xyz_s[q * 3 + 2] * 63.0f - (float)hz;
        float w = ((cls & 1) ? frx : 1.f - frx) *
                  (((cls >> 1) & 1) ? fry : 1.f - fry) *
                  (((cls >> 2) & 1) ? frz : 1.f - frz);
        wl[i] = make_int2(q, __float_as_int(w));
      }
      for (int i = slot; i < chunk; i += 8) {
        int2 v = wl[i];
        uint2 u = *(const uint2*)(featp + (size_t)v.x * NF + 4 * fq);
        float w = __int_as_float(v.y);
        acc.x = fmaf(w, bf2f((unsigned short)u.x), acc.x);
        acc.y = fmaf(w, bf2f((unsigned short)(u.x >> 16)), acc.y);
        acc.z = fmaf(w, bf2f((unsigned short)u.y), acc.z);
        acc.w = fmaf(w, bf2f((unsigned short)(u.y >> 16)), acc.w);
        wsum += w;
      }
    }
  } else {
    int cl = xcd_swz(dbid - 65536, 49152) * 4 + wave;  // [0, 196608)
    gcell = KO256Q + cl;
    featp = feat_g;
    int g = cl >> 16, m = cl & 65535;
    int cx = (int)c1b1((unsigned)m >> 1);
    int cy = (int)c1b1((unsigned)m);
    int beg[4], pre[4];
    int tot = 0;
#pragma unroll
    for (int cb = 0; cb < 4; ++cb) {
      int2 co = ccoff2[(size_t)cl * 4 + cb];
      pre[cb] = tot;
      beg[cb] = co.x;
      tot += co.y;
    }
    for (int cbase = 0; cbase < tot; cbase += 256) {
      int chunk = min(tot - cbase, 256);
      for (int i = lane; i < chunk; i += 64) {
        int ii = cbase + i;
        int cls = 0, b = beg[0], p0 = pre[0];
#pragma unroll
        for (int c2 = 1; c2 < 4; ++c2)
          if (ii >= pre[c2]) { cls = c2; b = beg[c2]; p0 = pre[c2]; }
        int q = b + (ii - p0);
        int hx = cx - ((cls >> 1) & 1), hy = cy - (cls & 1);
        float frx = xy_g[(size_t)q * 2 + 0] * 255.0f - (float)hx;
        float fry = xy_g[(size_t)q * 2 + 1] * 255.0f - (float)hy;
        float w = (((cls >> 1) & 1) ? frx : 1.f - frx) * ((cls & 1) ? fry : 1.f - fry);
        wl[i] = make_int2(q, __float_as_int(w));
      }
      for (int i = slot; i < chunk; i += 8) {
        int2 v = wl[i];
        uint2 u = *(const uint2*)(featp + (size_t)v.x * NF + 4 * fq);
        float w = __int_as_float(v.y);
        acc.x = fmaf(w, bf2f((unsigned short)u.x), acc.x);
        acc.y = fmaf(w, bf2f((unsigned short)(u.x >> 16)), acc.y);
        acc.z = fmaf(w, bf2f((unsigned short)u.y), acc.z);
        acc.w = fmaf(w, bf2f((unsigned short)(u.y >> 16)), acc.w);
        wsum += w;
      }
    }
  }
#pragma unroll
  for (int d = 8; d < 64; d <<= 1) {
    acc.x += __shfl_xor(acc.x, d);
    acc.y += __shfl_xor(acc.y, d);
    acc.z += __shfl_xor(acc.z, d);
    acc.w += __shfl_xor(acc.w, d);
    wsum += __shfl_xor(wsum, d);
  }
  if (slot == 0) {
    float inv = 1.f / fmaxf(wsum, EPSF);
    uint2 o;
    o.x = (unsigned)f2bf(acc.x * inv) | ((unsigned)f2bf(acc.y * inv) << 16);
    o.y = (unsigned)f2bf(acc.z * inv) | ((unsigned)f2bf(acc.w * inv) << 16);
    *(uint2*)(grid + (size_t)gcell * NF + 4 * fq) = o;
  }
}

// ---------------- fused encode: all 12 slots ----------------
__global__ __launch_bounds__(256) void encode_all(
    const float* __restrict__ xyz, const unsigned short* __restrict__ grid,
    float* __restrict__ out, int M) {
  int t = blockIdx.x * blockDim.x + threadIdx.x;
  int m = t >> 5, f = t & 31;
  if (m >= M) return;
  float X[3];
#pragma unroll
  for (int d = 0; d < 3; ++d) X[d] = xyz[m * 3 + d];
  {
    const int RS[3] = {16, 32, 64};
    const int KO[3] = {KO16, KO32, KO64};
#pragma unroll
    for (int r = 0; r < 3; ++r) {
      unsigned a0[3], a1[3];
      float fr[3];
#pragma unroll
      for (int d = 0; d < 3; ++d) {
        int i0 = cell_coord(X[d], RS[r], fr[d]);
        a0[d] = p1b2((unsigned)i0);
        a1[d] = p1b2((unsigned)(i0 + 1));
      }
      float acc = 0.f;
#pragma unroll
      for (int cb = 0; cb < 8; ++cb) {
        float w = 1.f;
        unsigned key = 0;
#pragma unroll
        for (int d = 0; d < 3; ++d) {
          int o = (cb >> d) & 1;
          w *= o ? fr[d] : (1.f - fr[d]);
          key |= (o ? a1[d] : a0[d]) << (2 - d);
        }
        acc = fmaf(w, bf2f(grid[(size_t)(KO[r] + (int)key) * NF + f]), acc);
      }
      out[(size_t)m * 384 + r * 32 + f] = acc;
    }
  }
  {
    const int RS[3] = {64, 128, 256};
    const int KB[3] = {KO64Q, KO128Q, KO256Q};
    const int RSQ[3] = {4096, 16384, 65536};
#pragma unroll
    for (int r = 0; r < 3; ++r) {
      unsigned b0[3], b1[3];
      float fr[3];
#pragma unroll
      for (int d = 0; d < 3; ++d) {
        int i0 = cell_coord(X[d], RS[r], fr[d]);
        b0[d] = p1b1((unsigned)i0);
        b1[d] = p1b1((unsigned)(i0 + 1));
      }
#pragma unroll
      for (int g = 0; g < 3; ++g) {
        int a = (g < 2) ? 0 : 1, b = (g == 0) ? 1 : 2;
        int base = KB[r] + g * RSQ[r];
        float acc = 0.f;
#pragma unroll
        for (int cb = 0; cb < 4; ++cb) {
          int o0 = (cb >> 1) & 1, o1 = cb & 1;
          float w = (o0 ? fr[a] : 1.f - fr[a]) * (o1 ? fr[b] : 1.f - fr[b]);
          int k = base + (int)(((o0 ? b1[a] : b0[a]) << 1) | (o1 ? b1[b] : b0[b]));
          acc = fmaf(w, bf2f(grid[(size_t)k * NF + f]), acc);
        }
        out[(size_t)m * 384 + (3 + g * 3 + r) * 32 + f] = acc;
      }
    }
  }
}

extern "C" void kernel_launch(void* const* d_in, const int* in_sizes, int n_in,
                              void* d_out, int out_size, void* d_ws, size_t ws_size,
                              hipStream_t stream) {
  const float* xyz_c = (const float*)d_in[0];
  const float* xyz_i = (const float*)d_in[1];
  const float* feat = (const float*)d_in[2];
  float* out = (float*)d_out;
  int N = in_sizes[0] / 3;
  int M = in_sizes[1] / 3;

  char* wsb = (char*)d_ws;
  size_t off = 0;
  auto al = [&](size_t bytes) {
    size_t o = off;
    off = (off + bytes + 255) & ~(size_t)255;
    return wsb + o;
  };
  const int KALL = KSORT + KVIS2;
  int* cnt_all = (int*)al((size_t)KALL * 4);
  int* cur_all = (int*)al((size_t)KALL * 4);
  int* bsum = (int*)al(4096);
  int* perm = (int*)al((size_t)4 * N * 4);
  float* xyz_s = (float*)al((size_t)N * 3 * 4);
  unsigned short* feat_s = (unsigned short*)al((size_t)N * NF * 2);
  float* xy_g = (float*)al((size_t)3 * N * 2 * 4);
  unsigned short* feat_g = (unsigned short*)al((size_t)3 * N * NF * 2);
  int2* visits = (int2*)al((size_t)40 * N * 8);
  unsigned short* grid = (unsigned short*)al((size_t)KVIS * NF * 2);
  int2* ccoff3 = (int2*)al((size_t)262144 * 8 * 8);
  int2* ccoff2 = (int2*)al((size_t)196608 * 4 * 8);

  int* cnt_v = cnt_all + KSORT;
  int* cur_v = cur_all + KSORT;

  int pb = (N + 255) / 256;
  int nbs = (KSORT + 2047) / 2048;
  int nbv = (KVIS2 + 2047) / 2048;

  hipMemsetAsync(cnt_all, 0, (size_t)KALL * 4, stream);

  // fused sort of all 4 point-orderings
  sort_hist_all<<<pb, 256, 0, stream>>>(xyz_c, cnt_all, N);
  scan_blocksum<<<nbs, 256, 0, stream>>>(cnt_all, bsum, KSORT);
  scan_write<<<nbs, 256, 0, stream>>>(cnt_all, bsum, cur_all, KSORT);
  sort_place_all<<<pb, 256, 0, stream>>>(xyz_c, cur_all, perm, N);
  permute_all<<<(4 * N * 32 + 255) / 256, 256, 0, stream>>>(xyz_c, feat, perm, xyz_s,
                                                            feat_s, xy_g, feat_g, N);

  // neighbor tables for fine grids (lane-parallel)
  stencil_coff<<<KSORT / 256, 256, 0, stream>>>(cnt_all, cur_all, ccoff3, ccoff2, N);

  // coarse visit lists only (fine grids go direct-gather)
  hist_fused<<<dim3(pb, 8), 256, 0, stream>>>(xyz_s, xy_g, cnt_v, N);
  scan_blocksum<<<nbv, 256, 0, stream>>>(cnt_v, bsum, KVIS2);
  scan_write<<<nbv, 256, 0, stream>>>(cnt_v, bsum, cur_v, KVIS2);
  place_fused<<<dim3(pb, 8), 256, 0, stream>>>(xyz_s, xy_g, cur_v, visits, N);

  // single fused create: coarse (98304 blocks) + fine direct (114688 blocks)
  create_all_fused<<<98304 + 114688, 256, 0, stream>>>(
      feat_s, feat_g, xyz_s, xy_g, cnt_v, cur_v, visits, ccoff3, ccoff2, grid, N);

  // fused encode: all 12 slots in one dispatch
  encode_all<<<(M * 32 + 255) / 256, 256, 0, stream>>>(xyz_i, grid, out, M);
}

// Round 21
// 691.960 us; speedup vs baseline: 1.9057x; 1.1019x over previous
//
#include <hip/hip_runtime.h>

#define NF 32
#define EPSF 1e-9f

// sort keyspace: [0,262144) morton3@64 ; [262144 + g*65536) pair g morton2@256
#define KSORT 458752
// coarse visit keyspace (visit lists only for coarse grids)
#define VO16 0
#define VO32 4096
#define VO64Q 36864
#define VO128Q 49152
#define KVIS2 98304
// grid layout (all 12 grids)
#define KO16 0
#define KO32 4096
#define KO64 36864
#define KO64Q 299008
#define KO128Q 311296
#define KO256Q 360448
#define KVIS 557056

__device__ __forceinline__ int cell_coord(float xv, int R, float& fr) {
  float x = xv * (float)(R - 1);
  int i0 = (int)floorf(x);
  i0 = min(max(i0, 0), R - 2);
  fr = x - (float)i0;
  return i0;
}
__device__ __forceinline__ float bf2f(unsigned short u) {
  return __uint_as_float((unsigned)u << 16);
}
__device__ __forceinline__ unsigned short f2bf(float x) {
  unsigned b = __float_as_uint(x);
  return (unsigned short)((b + 0x7FFF + ((b >> 16) & 1)) >> 16);
}
__device__ __forceinline__ unsigned p1b2(unsigned x) {
  x &= 0x3FF;
  x = (x | (x << 16)) & 0x030000FF;
  x = (x | (x << 8)) & 0x0300F00F;
  x = (x | (x << 4)) & 0x030C30C3;
  x = (x | (x << 2)) & 0x09249249;
  return x;
}
__device__ __forceinline__ unsigned p1b1(unsigned x) {
  x &= 0xFFFF;
  x = (x | (x << 8)) & 0x00FF00FF;
  x = (x | (x << 4)) & 0x0F0F0F0F;
  x = (x | (x << 2)) & 0x33333333;
  x = (x | (x << 1)) & 0x55555555;
  return x;
}
__device__ __forceinline__ unsigned c1b2(unsigned x) {
  x &= 0x09249249u;
  x = (x | (x >> 2)) & 0x030C30C3u;
  x = (x | (x >> 4)) & 0x0300F00Fu;
  x = (x | (x >> 8)) & 0x030000FFu;
  x = (x | (x >> 16)) & 0x3FFu;
  return x;
}
__device__ __forceinline__ unsigned c1b1(unsigned x) {
  x &= 0x55555555u;
  x = (x | (x >> 1)) & 0x33333333u;
  x = (x | (x >> 2)) & 0x0F0F0F0Fu;
  x = (x | (x >> 4)) & 0x00FF00FFu;
  x = (x | (x >> 8)) & 0xFFFFu;
  return x;
}

__device__ __forceinline__ int xcd_swz(int bid, int n) {
  return (bid & 7) * (n >> 3) + (bid >> 3);
}

// ---- wave-aggregated atomics over sorted-ish keys ----
__device__ __forceinline__ void agg_hist(int key, int* cnt) {
  int lane = threadIdx.x & 63;
  unsigned long long amask = __ballot(1);
  int nact = __popcll(amask);
  int prev = __shfl_up(key, 1);
  bool leader = (lane == 0) || (prev != key);
  unsigned long long lmask = __ballot(leader);
  if (leader) {
    unsigned long long above = (lane < 63) ? (lmask >> (lane + 1)) : 0ULL;
    int next = above ? (lane + 1 + (__ffsll((unsigned long long)above) - 1)) : nact;
    atomicAdd(&cnt[key], next - lane);
  }
}
template <int NC>
__device__ __forceinline__ void agg_place_batch(const int (&key)[NC], int* cur,
                                                int (&pos)[NC]) {
  int lane = threadIdx.x & 63;
  unsigned long long amask = __ballot(1);
  int nact = __popcll(amask);
  int ret[NC];
  int lp[NC];
#pragma unroll
  for (int c = 0; c < NC; ++c) {
    int prev = __shfl_up(key[c], 1);
    bool leader = (lane == 0) || (prev != key[c]);
    unsigned long long lmask = __ballot(leader);
    unsigned long long below = lmask & ((2ULL << lane) - 1ULL);
    lp[c] = 63 - __clzll((long long)below);
    ret[c] = 0;
    if (leader) {
      unsigned long long above = (lane < 63) ? (lmask >> (lane + 1)) : 0ULL;
      int next = above ? (lane + 1 + (__ffsll((unsigned long long)above) - 1)) : nact;
      ret[c] = atomicAdd(&cur[key[c]], next - lane);
    }
  }
#pragma unroll
  for (int c = 0; c < NC; ++c) pos[c] = __shfl(ret[c], lp[c]) + (lane - lp[c]);
}

// ---------------- fused sort keys: morton3@64 + 3 pair keys@256 ----------------
__global__ __launch_bounds__(256) void sort_hist_all(
    const float* __restrict__ xyz, int* __restrict__ cnt, int N) {
  int p = blockIdx.x * blockDim.x + threadIdx.x;
  if (p >= N) return;
  float fr;
  int c64[3], c256[3];
#pragma unroll
  for (int d = 0; d < 3; ++d) {
    c64[d] = cell_coord(xyz[p * 3 + d], 64, fr);
    c256[d] = cell_coord(xyz[p * 3 + d], 256, fr);
  }
  int k3 = (int)((p1b2((unsigned)c64[0]) << 2) | (p1b2((unsigned)c64[1]) << 1) |
                 p1b2((unsigned)c64[2]));
  atomicAdd(&cnt[k3], 1);
#pragma unroll
  for (int g = 0; g < 3; ++g) {
    int a = (g < 2) ? 0 : 1, b = (g == 0) ? 1 : 2;
    int key = 262144 + g * 65536 +
              (int)((p1b1((unsigned)c256[a]) << 1) | p1b1((unsigned)c256[b]));
    atomicAdd(&cnt[key], 1);
  }
}
__global__ __launch_bounds__(256) void sort_place_all(
    const float* __restrict__ xyz, int* __restrict__ cur, int* __restrict__ perm, int N) {
  int p = blockIdx.x * blockDim.x + threadIdx.x;
  if (p >= N) return;
  float fr;
  int c64[3], c256[3];
#pragma unroll
  for (int d = 0; d < 3; ++d) {
    c64[d] = cell_coord(xyz[p * 3 + d], 64, fr);
    c256[d] = cell_coord(xyz[p * 3 + d], 256, fr);
  }
  int k3 = (int)((p1b2((unsigned)c64[0]) << 2) | (p1b2((unsigned)c64[1]) << 1) |
                 p1b2((unsigned)c64[2]));
  perm[atomicAdd(&cur[k3], 1)] = p;
#pragma unroll
  for (int g = 0; g < 3; ++g) {
    int a = (g < 2) ? 0 : 1, b = (g == 0) ? 1 : 2;
    int key = 262144 + g * 65536 +
              (int)((p1b1((unsigned)c256[a]) << 1) | p1b1((unsigned)c256[b]));
    perm[atomicAdd(&cur[key], 1)] = p;
  }
}
__global__ __launch_bounds__(256) void permute_all(
    const float* __restrict__ xyz, const float* __restrict__ feat,
    const int* __restrict__ perm, float* __restrict__ xyz_s,
    unsigned short* __restrict__ feat_s, float* __restrict__ xy_g,
    unsigned short* __restrict__ feat_g, int N) {
  int t = blockIdx.x * blockDim.x + threadIdx.x;
  int s = t >> 5, f = t & 31;
  if (s >= 4 * N) return;
  int q = perm[s];
  float v = feat[(size_t)q * NF + f];
  if (s < N) {
    feat_s[(size_t)s * NF + f] = f2bf(v);
    if (f < 3) xyz_s[s * 3 + f] = xyz[q * 3 + f];
  } else {
    int sl = s - N;
    int g = sl / N;
    feat_g[(size_t)sl * NF + f] = f2bf(v);
    if (f < 2) {
      int a = (g < 2) ? 0 : 1, b = (g == 0) ? 1 : 2;
      xy_g[(size_t)sl * 2 + f] = xyz[q * 3 + (f == 0 ? a : b)];
    }
  }
}

// ---------------- scan (hierarchical, exclusive) ----------------
__global__ __launch_bounds__(256) void scan_blocksum(
    const int* __restrict__ cnt, int* __restrict__ bsum, int K) {
  __shared__ int red[256];
  int base = blockIdx.x * 2048 + threadIdx.x * 8;
  int s = 0;
#pragma unroll
  for (int j = 0; j < 8; ++j) {
    int k = base + j;
    if (k < K) s += cnt[k];
  }
  red[threadIdx.x] = s;
  __syncthreads();
  for (int off = 128; off > 0; off >>= 1) {
    if (threadIdx.x < off) red[threadIdx.x] += red[threadIdx.x + off];
    __syncthreads();
  }
  if (threadIdx.x == 0) bsum[blockIdx.x] = red[0];
}
__global__ __launch_bounds__(256) void scan_write(
    const int* __restrict__ cnt, const int* __restrict__ bsum,
    int* __restrict__ cur, int K) {
  __shared__ int lds[256];
  __shared__ int boff;
  int b = blockIdx.x, t = threadIdx.x;
  if (t == 0) {
    int s = 0;
    for (int j = 0; j < b; ++j) s += bsum[j];
    boff = s;
  }
  int base = b * 2048 + t * 8;
  int v[8];
  int s = 0;
#pragma unroll
  for (int j = 0; j < 8; ++j) {
    int k = base + j;
    v[j] = (k < K) ? cnt[k] : 0;
    s += v[j];
  }
  lds[t] = s;
  __syncthreads();
  for (int off = 1; off < 256; off <<= 1) {
    int add = (t >= off) ? lds[t - off] : 0;
    __syncthreads();
    lds[t] += add;
    __syncthreads();
  }
  int run = boff + lds[t] - s;
#pragma unroll
  for (int j = 0; j < 8; ++j) {
    int k = base + j;
    if (k < K) {
      cur[k] = run;
      run += v[j];
    }
  }
}

// ---------------- fused coarse hist: y=0..1 3D, y=2..7 2D(g,r) ----------------
__global__ __launch_bounds__(256) void hist_fused(
    const float* __restrict__ xyz_s, const float* __restrict__ xy_g,
    int* __restrict__ cnt, int N) {
  int y = blockIdx.y;
  int p = blockIdx.x * blockDim.x + threadIdx.x;
  if (p >= N) return;
  if (y < 2) {
    int R = 16 << y;
    int ko = (y == 0) ? VO16 : VO32;
    unsigned a0[3], a1[3];
    float fr[3];
#pragma unroll
    for (int d = 0; d < 3; ++d) {
      int i0 = cell_coord(xyz_s[p * 3 + d], R, fr[d]);
      a0[d] = p1b2((unsigned)i0);
      a1[d] = p1b2((unsigned)(i0 + 1));
    }
#pragma unroll
    for (int cb = 0; cb < 8; ++cb) {
      unsigned key = 0;
#pragma unroll
      for (int d = 0; d < 3; ++d) {
        int o = (cb >> d) & 1;
        key |= (o ? a1[d] : a0[d]) << (2 - d);
      }
      agg_hist(ko + (int)key, cnt);
    }
  } else {
    int idx = y - 2;
    int g = idx >> 1, r = idx & 1;
    int sl = g * N + p;
    int R = 64 << r;
    int kb = (r == 0) ? VO64Q : VO128Q;
    int base = kb + g * R * R;
    float frx, fry;
    int ix = cell_coord(xy_g[(size_t)sl * 2 + 0], R, frx);
    int iy = cell_coord(xy_g[(size_t)sl * 2 + 1], R, fry);
    unsigned ax0 = p1b1((unsigned)ix), ax1 = p1b1((unsigned)(ix + 1));
    unsigned ay0 = p1b1((unsigned)iy), ay1 = p1b1((unsigned)(iy + 1));
#pragma unroll
    for (int cb = 0; cb < 4; ++cb) {
      int o0 = (cb >> 1) & 1, o1 = cb & 1;
      agg_hist(base + (int)(((o0 ? ax1 : ax0) << 1) | (o1 ? ay1 : ay0)), cnt);
    }
  }
}

// ---------------- fused coarse placement (atomic): y=0..1 3D, y=2..7 2D ----------------
__global__ __launch_bounds__(256) void place_fused(
    const float* __restrict__ xyz_s, const float* __restrict__ xy_g,
    int* __restrict__ cur_v, int2* __restrict__ visits, int N) {
  int y = blockIdx.y;
  int p = blockIdx.x * blockDim.x + threadIdx.x;
  if (p >= N) return;
  if (y < 2) {
    int R = 16 << y;
    int ko = (y == 0) ? VO16 : VO32;
    unsigned a0[3], a1[3];
    float fr[3];
#pragma unroll
    for (int d = 0; d < 3; ++d) {
      int i0 = cell_coord(xyz_s[p * 3 + d], R, fr[d]);
      a0[d] = p1b2((unsigned)i0);
      a1[d] = p1b2((unsigned)(i0 + 1));
    }
    int keys[8];
    float ws[8];
#pragma unroll
    for (int cb = 0; cb < 8; ++cb) {
      float w = 1.f;
      unsigned key = 0;
#pragma unroll
      for (int d = 0; d < 3; ++d) {
        int o = (cb >> d) & 1;
        w *= o ? fr[d] : (1.f - fr[d]);
        key |= (o ? a1[d] : a0[d]) << (2 - d);
      }
      keys[cb] = ko + (int)key;
      ws[cb] = w;
    }
    int pos[8];
    agg_place_batch<8>(keys, cur_v, pos);
#pragma unroll
    for (int cb = 0; cb < 8; ++cb)
      visits[pos[cb]] = make_int2(p, __float_as_int(ws[cb]));
  } else {
    int idx = y - 2;
    int g = idx >> 1, r = idx & 1;
    int sl = g * N + p;
    int R = 64 << r;
    int kb = (r == 0) ? VO64Q : VO128Q;
    int base = kb + g * R * R;
    float frx, fry;
    int ix = cell_coord(xy_g[(size_t)sl * 2 + 0], R, frx);
    int iy = cell_coord(xy_g[(size_t)sl * 2 + 1], R, fry);
    unsigned ax0 = p1b1((unsigned)ix), ax1 = p1b1((unsigned)(ix + 1));
    unsigned ay0 = p1b1((unsigned)iy), ay1 = p1b1((unsigned)(iy + 1));
    int keys[4];
    float ws[4];
#pragma unroll
    for (int cb = 0; cb < 4; ++cb) {
      int o0 = (cb >> 1) & 1, o1 = cb & 1;
      ws[cb] = (o0 ? frx : 1.f - frx) * (o1 ? fry : 1.f - fry);
      keys[cb] = base + (int)(((o0 ? ax1 : ax0) << 1) | (o1 ? ay1 : ay0));
    }
    int pos[4];
    agg_place_batch<4>(keys, cur_v, pos);
#pragma unroll
    for (int cb = 0; cb < 4; ++cb)
      visits[pos[cb]] = make_int2(sl, __float_as_int(ws[cb]));
  }
}

// ---------------- stencil: per-cell (beg,cnt) neighbor tables (lane-parallel) ----------------
__global__ __launch_bounds__(256) void stencil_coff(
    const int* __restrict__ cnt_all, const int* __restrict__ cur_all,
    int2* __restrict__ ccoff3, int2* __restrict__ ccoff2, int N) {
  int t = blockIdx.x * 256 + threadIdx.x;  // < 458752
  if (t < 262144) {
    int c = t;
    int cx = (int)c1b2((unsigned)c >> 2), cy = (int)c1b2((unsigned)c >> 1),
        cz = (int)c1b2((unsigned)c);
#pragma unroll
    for (int cb = 0; cb < 8; ++cb) {
      int hx = cx - (cb & 1), hy = cy - ((cb >> 1) & 1), hz = cz - ((cb >> 2) & 1);
      int n = 0, b = 0;
      if (hx >= 0 && hy >= 0 && hz >= 0) {
        int hk = (int)((p1b2((unsigned)hx) << 2) | (p1b2((unsigned)hy) << 1) |
                       p1b2((unsigned)hz));
        n = cnt_all[hk];
        b = cur_all[hk] - n;
      }
      ccoff3[(size_t)c * 8 + cb] = make_int2(b, n);
    }
  } else {
    int t2 = t - 262144;
    int g = t2 >> 16, m = t2 & 65535;
    int cx = (int)c1b1((unsigned)m >> 1), cy = (int)c1b1((unsigned)m);
    const int* cntg = cnt_all + 262144 + g * 65536;
    const int* curg = cur_all + 262144 + g * 65536;
#pragma unroll
    for (int cb = 0; cb < 4; ++cb) {
      int hx = cx - ((cb >> 1) & 1), hy = cy - (cb & 1);
      int n = 0, b = 0;
      if (hx >= 0 && hy >= 0) {
        int hk = (int)((p1b1((unsigned)hx) << 1) | p1b1((unsigned)hy));
        n = cntg[hk];
        b = curg[hk] - n - N;  // index into xy_g/feat_g
      }
      ccoff2[(size_t)t2 * 4 + cb] = make_int2(b, n);
    }
  }
}

// ---------------- fused create: coarse visit-list + fine cell-per-lane-group ----------------
// bid < 98304: block-per-cell coarse; else fine: 8-lane group per cell (no LDS/reduction)
__global__ __launch_bounds__(256) void create_all_fused(
    const unsigned short* __restrict__ feat_s, const unsigned short* __restrict__ feat_g,
    const float* __restrict__ xyz_s, const float* __restrict__ xy_g,
    const int* __restrict__ cnt, const int* __restrict__ cur_end,
    const int2* __restrict__ visits, const int2* __restrict__ ccoff3,
    const int2* __restrict__ ccoff2, unsigned short* __restrict__ grid, int N) {
  __shared__ int2 vlds[1024];
  __shared__ float4 lacc4[256];
  __shared__ float lw[32];
  int bid = blockIdx.x;
  if (bid < 98304) {
    // ---- coarse: block-per-cell, 32 slots x 8 feature-quads ----
    int vo, go, base, nseg;
    const unsigned short* feat;
    if (bid < 4096) {
      vo = VO16; go = KO16; base = 0; nseg = 4096; feat = feat_s;
    } else if (bid < 36864) {
      vo = VO32; go = KO32; base = 4096; nseg = 32768; feat = feat_s;
    } else if (bid < 49152) {
      vo = VO64Q; go = KO64Q; base = 36864; nseg = 12288; feat = feat_g;
    } else {
      vo = VO128Q; go = KO128Q; base = 49152; nseg = 49152; feat = feat_g;
    }
    int idx = xcd_swz(bid - base, nseg);
    int vcell = vo + idx;
    int e = cur_end[vcell];
    int n = cnt[vcell];
    int beg = e - n;
    for (int i = threadIdx.x; i < n && i < 1024; i += 256) vlds[i] = visits[beg + i];
    __syncthreads();
    bool inl = (n <= 1024);
    int slot = threadIdx.x >> 3;  // 0..31
    int fq = threadIdx.x & 7;     // feature quad
    float4 acc = {0.f, 0.f, 0.f, 0.f};
    float wsum = 0.f;
    int i = slot;
    for (; i + 32 < n; i += 64) {
      int2 v0 = inl ? vlds[i] : visits[beg + i];
      int2 v1 = inl ? vlds[i + 32] : visits[beg + i + 32];
      uint2 u0 = *(const uint2*)(feat + (size_t)v0.x * NF + 4 * fq);
      uint2 u1 = *(const uint2*)(feat + (size_t)v1.x * NF + 4 * fq);
      float w0 = __int_as_float(v0.y), w1 = __int_as_float(v1.y);
      acc.x = fmaf(w0, bf2f((unsigned short)u0.x), acc.x);
      acc.y = fmaf(w0, bf2f((unsigned short)(u0.x >> 16)), acc.y);
      acc.z = fmaf(w0, bf2f((unsigned short)u0.y), acc.z);
      acc.w = fmaf(w0, bf2f((unsigned short)(u0.y >> 16)), acc.w);
      acc.x = fmaf(w1, bf2f((unsigned short)u1.x), acc.x);
      acc.y = fmaf(w1, bf2f((unsigned short)(u1.x >> 16)), acc.y);
      acc.z = fmaf(w1, bf2f((unsigned short)u1.y), acc.z);
      acc.w = fmaf(w1, bf2f((unsigned short)(u1.y >> 16)), acc.w);
      wsum += w0 + w1;
    }
    if (i < n) {
      int2 v = inl ? vlds[i] : visits[beg + i];
      uint2 u = *(const uint2*)(feat + (size_t)v.x * NF + 4 * fq);
      float w = __int_as_float(v.y);
      acc.x = fmaf(w, bf2f((unsigned short)u.x), acc.x);
      acc.y = fmaf(w, bf2f((unsigned short)(u.x >> 16)), acc.y);
      acc.z = fmaf(w, bf2f((unsigned short)u.y), acc.z);
      acc.w = fmaf(w, bf2f((unsigned short)(u.y >> 16)), acc.w);
      wsum += w;
    }
    lacc4[threadIdx.x] = acc;
    if (fq == 0) lw[slot] = wsum;
    __syncthreads();
    if (threadIdx.x < 8) {
      float4 a = {0.f, 0.f, 0.f, 0.f};
      float w = 0.f;
#pragma unroll
      for (int s = 0; s < 32; ++s) {
        float4 t2 = lacc4[s * 8 + threadIdx.x];
        a.x += t2.x;
        a.y += t2.y;
        a.z += t2.z;
        a.w += t2.w;
        w += lw[s];
      }
      float inv = 1.f / fmaxf(w, EPSF);
      uint2 o;
      o.x = (unsigned)f2bf(a.x * inv) | ((unsigned)f2bf(a.y * inv) << 16);
      o.y = (unsigned)f2bf(a.z * inv) | ((unsigned)f2bf(a.w * inv) << 16);
      *(uint2*)(grid + (size_t)(go + idx) * NF + 4 * threadIdx.x) = o;
    }
    return;
  }
  // ---- fine: 8-lane group per cell, features across lanes, visits serial ----
  int dbid = bid - 98304;
  int g8 = threadIdx.x >> 3;  // group 0..31 (cell within block)
  int fq = threadIdx.x & 7;   // feature quad
  float4 acc = {0.f, 0.f, 0.f, 0.f};
  float wsum = 0.f;
  int gcell;
  if (dbid < 8192) {
    int cell = xcd_swz(dbid, 8192) * 32 + g8;  // [0, 262144)
    gcell = KO64 + cell;
    int cx = (int)c1b2((unsigned)cell >> 2);
    int cy = (int)c1b2((unsigned)cell >> 1);
    int cz = (int)c1b2((unsigned)cell);
    int beg[8], pre[8];
    int tot = 0;
#pragma unroll
    for (int cb = 0; cb < 8; ++cb) {
      int2 co = ccoff3[(size_t)cell * 8 + cb];
      pre[cb] = tot;
      beg[cb] = co.x;
      tot += co.y;
    }
    for (int i = 0; i < tot; ++i) {
      int cls = 0, b = beg[0], p0 = pre[0];
#pragma unroll
      for (int c2 = 1; c2 < 8; ++c2)
        if (i >= pre[c2]) { cls = c2; b = beg[c2]; p0 = pre[c2]; }
      int q = b + (i - p0);
      int hx = cx - (cls & 1), hy = cy - ((cls >> 1) & 1), hz = cz - ((cls >> 2) & 1);
      float frx = xyz_s[q * 3 + 0] * 63.0f - (float)hx;
      float fry = xyz_s[q * 3 + 1] * 63.0f - (float)hy;
      float frz = xyz_s[q * 3 + 2] * 63.0f - (float)hz;
      float w = ((cls & 1) ? frx : 1.f - frx) *
                (((cls >> 1) & 1) ? fry : 1.f - fry) *
                (((cls >> 2) & 1) ? frz : 1.f - frz);
      uint2 u = *(const uint2*)(feat_s + (size_t)q * NF + 4 * fq);
      acc.x = fmaf(w, bf2f((unsigned short)u.x), acc.x);
      acc.y = fmaf(w, bf2f((unsigned short)(u.x >> 16)), acc.y);
      acc.z = fmaf(w, bf2f((unsigned short)u.y), acc.z);
      acc.w = fmaf(w, bf2f((unsigned short)(u.y >> 16)), acc.w);
      wsum += w;
    }
  } else {
    int cl = xcd_swz(dbid - 8192, 6144) * 32 + g8;  // [0, 196608)
    gcell = KO256Q + cl;
    int g = cl >> 16, m = cl & 65535;
    int cx = (int)c1b1((unsigned)m >> 1);
    int cy = (int)c1b1((unsigned)m);
    int beg[4], pre[4];
    int tot = 0;
#pragma unroll
    for (int cb = 0; cb < 4; ++cb) {
      int2 co = ccoff2[(size_t)cl * 4 + cb];
      pre[cb] = tot;
      beg[cb] = co.x;
      tot += co.y;
    }
    for (int i = 0; i < tot; ++i) {
      int cls = 0, b = beg[0], p0 = pre[0];
#pragma unroll
      for (int c2 = 1; c2 < 4; ++c2)
        if (i >= pre[c2]) { cls = c2; b = beg[c2]; p0 = pre[c2]; }
      int q = b + (i - p0);
      int hx = cx - ((cls >> 1) & 1), hy = cy - (cls & 1);
      float frx = xy_g[(size_t)q * 2 + 0] * 255.0f - (float)hx;
      float fry = xy_g[(size_t)q * 2 + 1] * 255.0f - (float)hy;
      float w = (((cls >> 1) & 1) ? frx : 1.f - frx) * ((cls & 1) ? fry : 1.f - fry);
      uint2 u = *(const uint2*)(feat_g + (size_t)q * NF + 4 * fq);
      acc.x = fmaf(w, bf2f((unsigned short)u.x), acc.x);
      acc.y = fmaf(w, bf2f((unsigned short)(u.x >> 16)), acc.y);
      acc.z = fmaf(w, bf2f((unsigned short)u.y), acc.z);
      acc.w = fmaf(w, bf2f((unsigned short)(u.y >> 16)), acc.w);
      wsum += w;
    }
  }
  float inv = 1.f / fmaxf(wsum, EPSF);
  uint2 o;
  o.x = (unsigned)f2bf(acc.x * inv) | ((unsigned)f2bf(acc.y * inv) << 16);
  o.y = (unsigned)f2bf(acc.z * inv) | ((unsigned)f2bf(acc.w * inv) << 16);
  *(uint2*)(grid + (size_t)gcell * NF + 4 * fq) = o;
}

// ---------------- fused encode: all 12 slots ----------------
__global__ __launch_bounds__(256) void encode_all(
    const float* __restrict__ xyz, const unsigned short* __restrict__ grid,
    float* __restrict__ out, int M) {
  int t = blockIdx.x * blockDim.x + threadIdx.x;
  int m = t >> 5, f = t & 31;
  if (m >= M) return;
  float X[3];
#pragma unroll
  for (int d = 0; d < 3; ++d) X[d] = xyz[m * 3 + d];
  {
    const int RS[3] = {16, 32, 64};
    const int KO[3] = {KO16, KO32, KO64};
#pragma unroll
    for (int r = 0; r < 3; ++r) {
      unsigned a0[3], a1[3];
      float fr[3];
#pragma unroll
      for (int d = 0; d < 3; ++d) {
        int i0 = cell_coord(X[d], RS[r], fr[d]);
        a0[d] = p1b2((unsigned)i0);
        a1[d] = p1b2((unsigned)(i0 + 1));
      }
      float acc = 0.f;
#pragma unroll
      for (int cb = 0; cb < 8; ++cb) {
        float w = 1.f;
        unsigned key = 0;
#pragma unroll
        for (int d = 0; d < 3; ++d) {
          int o = (cb >> d) & 1;
          w *= o ? fr[d] : (1.f - fr[d]);
          key |= (o ? a1[d] : a0[d]) << (2 - d);
        }
        acc = fmaf(w, bf2f(grid[(size_t)(KO[r] + (int)key) * NF + f]), acc);
      }
      out[(size_t)m * 384 + r * 32 + f] = acc;
    }
  }
  {
    const int RS[3] = {64, 128, 256};
    const int KB[3] = {KO64Q, KO128Q, KO256Q};
    const int RSQ[3] = {4096, 16384, 65536};
#pragma unroll
    for (int r = 0; r < 3; ++r) {
      unsigned b0[3], b1[3];
      float fr[3];
#pragma unroll
      for (int d = 0; d < 3; ++d) {
        int i0 = cell_coord(X[d], RS[r], fr[d]);
        b0[d] = p1b1((unsigned)i0);
        b1[d] = p1b1((unsigned)(i0 + 1));
      }
#pragma unroll
      for (int g = 0; g < 3; ++g) {
        int a = (g < 2) ? 0 : 1, b = (g == 0) ? 1 : 2;
        int base = KB[r] + g * RSQ[r];
        float acc = 0.f;
#pragma unroll
        for (int cb = 0; cb < 4; ++cb) {
          int o0 = (cb >> 1) & 1, o1 = cb & 1;
          float w = (o0 ? fr[a] : 1.f - fr[a]) * (o1 ? fr[b] : 1.f - fr[b]);
          int k = base + (int)(((o0 ? b1[a] : b0[a]) << 1) | (o1 ? b1[b] : b0[b]));
          acc = fmaf(w, bf2f(grid[(size_t)k * NF + f]), acc);
        }
        out[(size_t)m * 384 + (3 + g * 3 + r) * 32 + f] = acc;
      }
    }
  }
}

extern "C" void kernel_launch(void* const* d_in, const int* in_sizes, int n_in,
                              void* d_out, int out_size, void* d_ws, size_t ws_size,
                              hipStream_t stream) {
  const float* xyz_c = (const float*)d_in[0];
  const float* xyz_i = (const float*)d_in[1];
  const float* feat = (const float*)d_in[2];
  float* out = (float*)d_out;
  int N = in_sizes[0] / 3;
  int M = in_sizes[1] / 3;

  char* wsb = (char*)d_ws;
  size_t off = 0;
  auto al = [&](size_t bytes) {
    size_t o = off;
    off = (off + bytes + 255) & ~(size_t)255;
    return wsb + o;
  };
  const int KALL = KSORT + KVIS2;
  int* cnt_all = (int*)al((size_t)KALL * 4);
  int* cur_all = (int*)al((size_t)KALL * 4);
  int* bsum = (int*)al(4096);
  int* perm = (int*)al((size_t)4 * N * 4);
  float* xyz_s = (float*)al((size_t)N * 3 * 4);
  unsigned short* feat_s = (unsigned short*)al((size_t)N * NF * 2);
  float* xy_g = (float*)al((size_t)3 * N * 2 * 4);
  unsigned short* feat_g = (unsigned short*)al((size_t)3 * N * NF * 2);
  int2* visits = (int2*)al((size_t)40 * N * 8);
  unsigned short* grid = (unsigned short*)al((size_t)KVIS * NF * 2);
  int2* ccoff3 = (int2*)al((size_t)262144 * 8 * 8);
  int2* ccoff2 = (int2*)al((size_t)196608 * 4 * 8);

  int* cnt_v = cnt_all + KSORT;
  int* cur_v = cur_all + KSORT;

  int pb = (N + 255) / 256;
  int nbs = (KSORT + 2047) / 2048;
  int nbv = (KVIS2 + 2047) / 2048;

  hipMemsetAsync(cnt_all, 0, (size_t)KALL * 4, stream);

  // fused sort of all 4 point-orderings
  sort_hist_all<<<pb, 256, 0, stream>>>(xyz_c, cnt_all, N);
  scan_blocksum<<<nbs, 256, 0, stream>>>(cnt_all, bsum, KSORT);
  scan_write<<<nbs, 256, 0, stream>>>(cnt_all, bsum, cur_all, KSORT);
  sort_place_all<<<pb, 256, 0, stream>>>(xyz_c, cur_all, perm, N);
  permute_all<<<(4 * N * 32 + 255) / 256, 256, 0, stream>>>(xyz_c, feat, perm, xyz_s,
                                                            feat_s, xy_g, feat_g, N);

  // neighbor tables for fine grids (lane-parallel)
  stencil_coff<<<KSORT / 256, 256, 0, stream>>>(cnt_all, cur_all, ccoff3, ccoff2, N);

  // coarse visit lists only (fine grids go direct-gather)
  hist_fused<<<dim3(pb, 8), 256, 0, stream>>>(xyz_s, xy_g, cnt_v, N);
  scan_blocksum<<<nbv, 256, 0, stream>>>(cnt_v, bsum, KVIS2);
  scan_write<<<nbv, 256, 0, stream>>>(cnt_v, bsum, cur_v, KVIS2);
  place_fused<<<dim3(pb, 8), 256, 0, stream>>>(xyz_s, xy_g, cur_v, visits, N);

  // single fused create: coarse (98304 blocks) + fine lane-group (14336 blocks)
  create_all_fused<<<98304 + 14336, 256, 0, stream>>>(
      feat_s, feat_g, xyz_s, xy_g, cnt_v, cur_v, visits, ccoff3, ccoff2, grid, N);

  // fused encode: all 12 slots in one dispatch
  encode_all<<<(M * 32 + 255) / 256, 256, 0, stream>>>(xyz_i, grid, out, M);
}